// Round 6
// baseline (3537.659 us; speedup 1.0000x reference)
//
#include <hip/hip_runtime.h>
#include <hip/hip_bf16.h>

#define BATCH 32
#define SEQ   512
#define IND   1024
#define HD    1024
#define ZD    2048   // IN + H
#define NG    4096   // 4*H
#define WG_ELEMS (1024 * 2048)   // elements per gate weight matrix
#define PBLK 128                 // persistent grid size

typedef short  shortx8 __attribute__((ext_vector_type(8)));
typedef float  floatx4 __attribute__((ext_vector_type(4)));

#define MFMA16(a, b, c) __builtin_amdgcn_mfma_f32_16x16x32_bf16((a), (b), (c), 0, 0, 0)

__device__ __forceinline__ float sigmoidf_(float x) {
    return 1.0f / (1.0f + __expf(-x));
}
__device__ __forceinline__ float tanhf_(float x) {
    return 1.0f - 2.0f / (__expf(2.0f * x) + 1.0f);
}

__device__ __forceinline__ short bf16s(float x) {
    __hip_bfloat16 h = __float2bfloat16(x);
    return *reinterpret_cast<short*>(&h);
}

__device__ __forceinline__ shortx8 cvt8(const float* __restrict__ p) {
    float4 v0 = *(const float4*)p;
    float4 v1 = *(const float4*)(p + 4);
    shortx8 r;
    r[0] = bf16s(v0.x); r[1] = bf16s(v0.y); r[2] = bf16s(v0.z); r[3] = bf16s(v0.w);
    r[4] = bf16s(v1.x); r[5] = bf16s(v1.y); r[6] = bf16s(v1.z); r[7] = bf16s(v1.w);
    return r;
}

// ---------------------------------------------------------------------------
// fp32 -> bf16 conversion (weights + x). n % 4 == 0. grid-stride not needed.
// ---------------------------------------------------------------------------
__global__ __launch_bounds__(256) void cvt_f32_bf16(
    const float* __restrict__ src, __hip_bfloat16* __restrict__ dst, int n)
{
    int i = (blockIdx.x * 256 + threadIdx.x) * 4;
    if (i < n) {
        float4 v = *(const float4*)(src + i);
        dst[i + 0] = __float2bfloat16(v.x);
        dst[i + 1] = __float2bfloat16(v.y);
        dst[i + 2] = __float2bfloat16(v.z);
        dst[i + 3] = __float2bfloat16(v.w);
    }
}

// ---------------------------------------------------------------------------
// Kernel 1 (FALLBACK only): x-part gate pre-activations for a chunk of T
// steps. Gx[(t-t0)*B + b][g*1024+j] = sum_k x[b][t][k]*Wg[j][1024+k] + bias.
// grid = T*8 blocks of 256.
// ---------------------------------------------------------------------------
__global__ __launch_bounds__(256) void gemm_gx(
    const float* __restrict__ x,
    const __hip_bfloat16* __restrict__ Wb,     // [4][1024][2048] bf16
    const float* __restrict__ bf_, const float* __restrict__ bi_,
    const float* __restrict__ bc_, const float* __restrict__ bo_,
    __hip_bfloat16* __restrict__ Gx, const int t0)
{
    const int wave = (blockIdx.x << 2) + (threadIdx.x >> 6);
    const int mt = wave >> 6;
    const int nt = wave & 63;
    const int lane = threadIdx.x & 63;
    const int quad = lane >> 4;
    const int l16  = lane & 15;
    const int m0 = mt << 6;
    const int n0 = nt << 6;
    const int g  = n0 >> 10;
    const __hip_bfloat16* Wg = Wb + (size_t)g * WG_ELEMS;
    const float* bg = (g == 0) ? bf_ : (g == 1) ? bi_ : (g == 2) ? bc_ : bo_;
    const int j0 = n0 & 1023;

    floatx4 acc[4][4];
#pragma unroll
    for (int i = 0; i < 4; i++)
#pragma unroll
        for (int j = 0; j < 4; j++) acc[i][j] = (floatx4)(0.0f);

    const float* arow[4];
    const __hip_bfloat16* brow[4];
#pragma unroll
    for (int i = 0; i < 4; i++) {
        const int r = m0 + i * 16 + l16;
        const int t = t0 + (r >> 5);
        const int b = r & 31;
        arow[i] = x + ((size_t)b * SEQ + t) * IND + quad * 8;
    }
#pragma unroll
    for (int j = 0; j < 4; j++)
        brow[j] = Wg + (size_t)(j0 + j * 16 + l16) * ZD + HD + quad * 8;

    for (int k0 = 0; k0 < IND; k0 += 32) {
        shortx8 a[4], b[4];
#pragma unroll
        for (int i = 0; i < 4; i++) a[i] = cvt8(arow[i] + k0);
#pragma unroll
        for (int j = 0; j < 4; j++) b[j] = *(const shortx8*)(brow[j] + k0);
#pragma unroll
        for (int i = 0; i < 4; i++)
#pragma unroll
            for (int j = 0; j < 4; j++)
                acc[i][j] = MFMA16(a[i], b[j], acc[i][j]);
    }

#pragma unroll
    for (int j = 0; j < 4; j++) {
        const int n  = n0 + j * 16 + l16;
        const int jj = j0 + j * 16 + l16;
        const float bias = bg[jj];
#pragma unroll
        for (int i = 0; i < 4; i++) {
#pragma unroll
            for (int r = 0; r < 4; r++) {
                const int row = m0 + i * 16 + quad * 4 + r;
                Gx[(size_t)row * NG + n] = __float2bfloat16(acc[i][j][r] + bias);
            }
        }
    }
}

// ---------------------------------------------------------------------------
// Kernel 2 (FALLBACK, small-ws path): one LSTM time step, hs-direct h I/O.
// ---------------------------------------------------------------------------
__global__ __launch_bounds__(256) void lstm_step(
    const __hip_bfloat16* __restrict__ gx,
    const int t,
    const __hip_bfloat16* __restrict__ Wb,
    const __hip_bfloat16* __restrict__ hzero,  // [B][H] zeros
    float* __restrict__ c,
    __hip_bfloat16* __restrict__ hs)           // [B][S][H]
{
    const int jt = (blockIdx.x << 2) + (threadIdx.x >> 6);
    const int lane = threadIdx.x & 63;
    const int quad = lane >> 4;
    const int l16  = lane & 15;
    const int j0   = jt << 4;

    const __hip_bfloat16* hb;
    size_t rstride;
    if (t == 0) { hb = hzero; rstride = HD; }
    else        { hb = hs + (size_t)(t - 1) * HD; rstride = (size_t)SEQ * HD; }

    const __hip_bfloat16* wrow[4];
#pragma unroll
    for (int g = 0; g < 4; g++)
        wrow[g] = Wb + (size_t)g * WG_ELEMS + (size_t)(j0 + l16) * ZD + quad * 8;

    const __hip_bfloat16* hrow0 = hb + (size_t)l16 * rstride + quad * 8;
    const __hip_bfloat16* hrow1 = hb + (size_t)(16 + l16) * rstride + quad * 8;

    floatx4 acc[4][2];
#pragma unroll
    for (int g = 0; g < 4; g++) { acc[g][0] = (floatx4)(0.0f); acc[g][1] = (floatx4)(0.0f); }

    for (int k0 = 0; k0 < HD; k0 += 32) {
        shortx8 a0 = *(const shortx8*)(hrow0 + k0);
        shortx8 a1 = *(const shortx8*)(hrow1 + k0);
#pragma unroll
        for (int g = 0; g < 4; g++) {
            shortx8 bfrag = *(const shortx8*)(wrow[g] + k0);
            acc[g][0] = MFMA16(a0, bfrag, acc[g][0]);
            acc[g][1] = MFMA16(a1, bfrag, acc[g][1]);
        }
    }

    const int j = j0 + l16;
#pragma unroll
    for (int i = 0; i < 2; i++) {
#pragma unroll
        for (int r = 0; r < 4; r++) {
            const int bb = i * 16 + quad * 4 + r;
            const size_t gbase = (size_t)bb * NG + j;
            const float fp = acc[0][i][r] + __bfloat162float(gx[gbase + 0 * HD]);
            const float ip = acc[1][i][r] + __bfloat162float(gx[gbase + 1 * HD]);
            const float cp = acc[2][i][r] + __bfloat162float(gx[gbase + 2 * HD]);
            const float op = acc[3][i][r] + __bfloat162float(gx[gbase + 3 * HD]);
            const float fg = sigmoidf_(fp);
            const float ig = sigmoidf_(ip);
            const float cg = tanhf_(cp);
            const float og = sigmoidf_(op);
            const size_t ci = (size_t)bb * HD + j;
            const float cnew = ig * cg + fg * c[ci];
            const float hnew = og * tanhf_(cnew);
            c[ci] = cnew;
            hs[((size_t)bb * SEQ + t) * HD + j] = __float2bfloat16(hnew);
        }
    }
}

// ---------------------------------------------------------------------------
// Kernel 2' (FAST path): persistent fused recurrence, v8.
// 128 blocks x 512 threads (8 waves).
//   Waves 0-3 (CONSUMERS) = v7 structure verbatim: wave (wm=batch-half,
//     wk=K-half) computes both 16-col tiles of h@Wh^T over K=512 from
//     global hs[t-1]; 2-panel LDS reduce; pointwise on tid<256.
//   Waves 4-7 (PRODUCERS) = gemm_gx fused in: during step tt they compute
//     next step's x-part pre-activations gx[tt+1] for THIS block's 32
//     gate-rows (x[t+1] @ Wx-part, K=1024 split 2 ways, 32 MFMA/wave)
//     into an LDS ring (depth 2). Block blk consumes exactly the Gx slice
//     it produces -> Gx never exists in global memory; the serial gemm_gx
//     launch (~720us) is deleted. Producer work hides under the consumer
//     phase's IF latency + barrier poll (independent work, off the
//     critical path -- unlike v4's dependent wave-split).
// Bias is added in the pointwise (was folded into Gx).
// x is pre-converted to bf16 by the host (cvt launch, ~15us).
//
// Sync: the existing per-step __syncthreads orders producer LDS writes
// (ring[(tt+1)&1]) against pointwise reads (ring[tt&1]); ring depth 2 +
// the end-of-step barrier excludes WAR hazards. Device barrier unchanged
// from v5/v7 (distributed arrive flags, relaxed sc1, parallel lane poll).
// ---------------------------------------------------------------------------
__global__ __launch_bounds__(512, 1) void lstm_persist(
    const __hip_bfloat16* __restrict__ Wb,     // [4][1024][2048] bf16
    const __hip_bfloat16* __restrict__ xb,     // [B][S][IND] bf16
    const float* __restrict__ bf_, const float* __restrict__ bi_,
    const float* __restrict__ bc_, const float* __restrict__ bo_,
    const int t0, const int T,
    const __hip_bfloat16* __restrict__ hzero,  // [B][H] zeros
    float* __restrict__ c_ws,                  // [PBLK*256] fp32
    __hip_bfloat16* __restrict__ hs,           // [B][S][H] bf16
    unsigned* __restrict__ bar)                // arrive[PBLK] slots, stride 16 u32
{
    // consumer h-panels [wk][col*36+b] and producer gx ring [2][wk][col*36+b]
    __shared__ float accf[2 * 1168];
    __shared__ float gxp[2][2 * 1168];

    const int tid  = threadIdx.x;
    const int blk  = blockIdx.x;
    const int wv   = tid >> 6;        // 0..7
    const int lane = tid & 63;
    const int quad = lane >> 4;
    const int l16  = lane & 15;
    const bool prod = wv >= 4;
    const int sv   = wv & 3;
    const int wm   = sv & 1;          // batch-half tile
    const int wk   = sv >> 1;         // K-half

    // --- B fragments, loaded once per launch ---
    // col (= ct*16 + l16, 0..31) <-> gate-row (g = col&3, j = blk*8 + (col>>2))
    // consumers: h-part cols [wk*512 ..); producers: x-part cols [HD + wk*512 ..)
    shortx8 Bfrag[2][16];
    {
        const int kbase = (prod ? HD : 0) + wk * 512;
#pragma unroll
        for (int ct = 0; ct < 2; ct++) {
            const int lc = ct * 16 + l16;
            const int jj = lc >> 2, g = lc & 3;
            const __hip_bfloat16* wr =
                Wb + (size_t)g * WG_ELEMS + (size_t)(blk * 8 + jj) * ZD + kbase + quad * 8;
#pragma unroll
            for (int ks = 0; ks < 16; ks++)
                Bfrag[ct][ks] = *(const shortx8*)(wr + ks * 32);
        }
    }

    // pointwise mapping (tid < 256 = consumer waves)
    const int pjj = tid & 7;
    const int pb  = tid >> 3;
    const int pj  = blk * 8 + pjj;
    float creg = 0.0f;
    float bias4[4] = {0.0f, 0.0f, 0.0f, 0.0f};
    if (tid < 256) {
        creg = c_ws[blk * 256 + tid];
        bias4[0] = bf_[pj]; bias4[1] = bi_[pj];
        bias4[2] = bc_[pj]; bias4[3] = bo_[pj];
    }

    // producer pass: gx partials for time tg into ring panel `ring`
    auto producer_pass = [&](int tg, float* ring) {
        const __hip_bfloat16* arow =
            xb + ((size_t)(wm * 16 + l16) * SEQ + tg) * IND + wk * 512 + quad * 8;
        floatx4 a0 = (floatx4)(0.0f), a1 = (floatx4)(0.0f);
#pragma unroll
        for (int ks = 0; ks < 16; ks++) {
            shortx8 av = *(const shortx8*)(arow + ks * 32);
            a0 = MFMA16(av, Bfrag[0][ks], a0);
            a1 = MFMA16(av, Bfrag[1][ks], a1);
        }
        const int b0 = wm * 16 + quad * 4;
        *(floatx4*)(ring + wk * 1168 + (l16)      * 36 + b0) = a0;
        *(floatx4*)(ring + wk * 1168 + (16 + l16) * 36 + b0) = a1;
    };

    // prologue: producers fill ring[0] with gx for step 0 (ordered vs the
    // pointwise of step 0 by the first mid-step __syncthreads)
    if (prod && T > 0) producer_pass(t0, gxp[0]);

    for (int tt = 0; tt < T; tt++) {
        const int t = t0 + tt;

        if (!prod) {
            // h @ Wh^T : one A-frag stream feeds BOTH col-tile chains
            const __hip_bfloat16* hb;
            size_t rstride;
            if (t == 0) { hb = hzero; rstride = HD; }
            else        { hb = hs + (size_t)(t - 1) * HD; rstride = (size_t)SEQ * HD; }
            const __hip_bfloat16* arow =
                hb + (size_t)(wm * 16 + l16) * rstride + wk * 512 + quad * 8;
            floatx4 acc0 = (floatx4)(0.0f), acc1 = (floatx4)(0.0f);
#pragma unroll
            for (int ks = 0; ks < 16; ks++) {
                shortx8 av = *(const shortx8*)(arow + ks * 32);
                acc0 = MFMA16(av, Bfrag[0][ks], acc0);
                acc1 = MFMA16(av, Bfrag[1][ks], acc1);
            }
            const int b0 = wm * 16 + quad * 4;
            *(floatx4*)(accf + wk * 1168 + (l16)      * 36 + b0) = acc0;
            *(floatx4*)(accf + wk * 1168 + (16 + l16) * 36 + b0) = acc1;
        } else {
            // produce NEXT step's gx into the other ring panel
            if (tt + 1 < T) producer_pass(t0 + tt + 1, gxp[(tt + 1) & 1]);
        }
        __syncthreads();

        // pointwise for (pb, pjj); c lives in a register across the launch
        if (tid < 256) {
            const float* gxr = gxp[tt & 1];
            const int i0 = (pjj * 4 + 0) * 36 + pb;
            const int i1 = (pjj * 4 + 1) * 36 + pb;
            const int i2 = (pjj * 4 + 2) * 36 + pb;
            const int i3 = (pjj * 4 + 3) * 36 + pb;
            const float fp = accf[i0] + accf[1168 + i0] + gxr[i0] + gxr[1168 + i0] + bias4[0];
            const float ip = accf[i1] + accf[1168 + i1] + gxr[i1] + gxr[1168 + i1] + bias4[1];
            const float cp = accf[i2] + accf[1168 + i2] + gxr[i2] + gxr[1168 + i2] + bias4[2];
            const float op = accf[i3] + accf[1168 + i3] + gxr[i3] + gxr[1168 + i3] + bias4[3];
            const float fg = sigmoidf_(fp);
            const float ig = sigmoidf_(ip);
            const float cg = tanhf_(cp);
            const float og = sigmoidf_(op);
            creg = ig * cg + fg * creg;
            const float hnew = og * tanhf_(creg);

            // packed-u32 relaxed agent store (sc1 => coherence-point visible)
            const unsigned my = (unsigned)(unsigned short)bf16s(hnew);
            const unsigned nb = (unsigned)__shfl_xor((int)my, 1);
            if ((tid & 1) == 0) {
                unsigned* dst = (unsigned*)(hs + ((size_t)pb * SEQ + t) * HD + pj);
                const unsigned packed = my | (nb << 16);
                __hip_atomic_store(dst, packed, __ATOMIC_RELAXED,
                                   __HIP_MEMORY_SCOPE_AGENT);
            }
        }

        // device barrier (not needed after the last step)
        if (tt < T - 1) {
            __syncthreads();   // per-wave s_waitcnt vmcnt(0): sc1 stores at IF
            const unsigned epoch = (unsigned)(tt + 1);
            if (wv == 0) {
                if (lane == 0) {
                    __hip_atomic_store(bar + blk * 16, epoch, __ATOMIC_RELAXED,
                                       __HIP_MEMORY_SCOPE_AGENT);
                }
                // parallel poll: lane L watches slots L and L+64 (sticky)
                unsigned* p0 = bar + lane * 16;
                unsigned* p1 = bar + (64 + lane) * 16;
                bool d0 = false, d1 = false;
                while (true) {
                    if (!d0) d0 = (__hip_atomic_load(p0, __ATOMIC_RELAXED,
                                       __HIP_MEMORY_SCOPE_AGENT) >= epoch);
                    if (!d1) d1 = (__hip_atomic_load(p1, __ATOMIC_RELAXED,
                                       __HIP_MEMORY_SCOPE_AGENT) >= epoch);
                    if (__all(d0 && d1)) break;
                    __builtin_amdgcn_s_sleep(1);
                }
                asm volatile("" ::: "memory");
                __builtin_amdgcn_sched_barrier(0);
            }
            __syncthreads();
        }
    }

    if (tid < 256) c_ws[blk * 256 + tid] = creg;
}

// ---------------------------------------------------------------------------
// Kernel 3: out[r][n] = sum_k hs[r][k] * Wfc[n][k] + bfc[n]   (fp32 out)
// ---------------------------------------------------------------------------
__global__ __launch_bounds__(256) void gemm_fc(
    const __hip_bfloat16* __restrict__ hs,
    const __hip_bfloat16* __restrict__ Wfcb,
    const float* __restrict__ bfc,
    float* __restrict__ out)
{
    const int wave = (blockIdx.x << 2) + (threadIdx.x >> 6);
    const int mt = wave >> 4;
    const int nt = wave & 15;
    const int lane = threadIdx.x & 63;
    const int quad = lane >> 4;
    const int l16  = lane & 15;
    const int m0 = mt << 6;
    const int n0 = nt << 6;

    floatx4 acc[4][4];
#pragma unroll
    for (int i = 0; i < 4; i++)
#pragma unroll
        for (int j = 0; j < 4; j++) acc[i][j] = (floatx4)(0.0f);

    const __hip_bfloat16* arow[4];
    const __hip_bfloat16* brow[4];
#pragma unroll
    for (int i = 0; i < 4; i++)
        arow[i] = hs + (size_t)(m0 + i * 16 + l16) * HD + quad * 8;
#pragma unroll
    for (int j = 0; j < 4; j++)
        brow[j] = Wfcb + (size_t)(n0 + j * 16 + l16) * HD + quad * 8;

    for (int k0 = 0; k0 < HD; k0 += 32) {
        shortx8 a[4], b[4];
#pragma unroll
        for (int i = 0; i < 4; i++) a[i] = *(const shortx8*)(arow[i] + k0);
#pragma unroll
        for (int j = 0; j < 4; j++) b[j] = *(const shortx8*)(brow[j] + k0);
#pragma unroll
        for (int i = 0; i < 4; i++)
#pragma unroll
            for (int j = 0; j < 4; j++)
                acc[i][j] = MFMA16(a[i], b[j], acc[i][j]);
    }

#pragma unroll
    for (int j = 0; j < 4; j++) {
        const int n = n0 + j * 16 + l16;
        const float bias = bfc[n];
#pragma unroll
        for (int i = 0; i < 4; i++) {
#pragma unroll
            for (int r = 0; r < 4; r++) {
                const int row = m0 + i * 16 + quad * 4 + r;
                out[(size_t)row * 1024 + n] = acc[i][j][r] + bias;
            }
        }
    }
}

// ---------------------------------------------------------------------------
extern "C" void kernel_launch(void* const* d_in, const int* in_sizes, int n_in,
                              void* d_out, int out_size, void* d_ws, size_t ws_size,
                              hipStream_t stream) {
    const float* x   = (const float*)d_in[0];
    const float* Wf  = (const float*)d_in[1];
    const float* bf_ = (const float*)d_in[2];
    const float* Wi  = (const float*)d_in[3];
    const float* bi_ = (const float*)d_in[4];
    const float* Wc  = (const float*)d_in[5];
    const float* bc_ = (const float*)d_in[6];
    const float* Wo  = (const float*)d_in[7];
    const float* bo_ = (const float*)d_in[8];
    const float* Wfc = (const float*)d_in[9];
    const float* bfc = (const float*)d_in[10];
    float* out = (float*)d_out;

    // ---- ws layout (bytes) ----
    char* ws = (char*)d_ws;
    const size_t WB_OFF  = 0;                                          // 16 MiB
    const size_t WFC_OFF = (size_t)4 * WG_ELEMS * 2;                   // +2 MiB
    const size_t HS_OFF  = WFC_OFF + (size_t)HD * HD * 2;              // +32 MiB
    const size_t ST_OFF  = HS_OFF + (size_t)BATCH * SEQ * HD * 2;
    const size_t HZ_BYTES  = (size_t)BATCH * HD * 2;                   // 64 KiB
    const size_t C_BYTES   = (size_t)PBLK * 256 * 4;                   // 128 KiB
    const size_t BAR_BYTES = (size_t)PBLK * 64;                        // arrive slots
    const size_t ST_BYTES  = HZ_BYTES + C_BYTES + BAR_BYTES;
    const size_t GX_OFF  = ST_OFF + ST_BYTES;     // fallback Gx OR persist xb (union)

    __hip_bfloat16* Wb    = (__hip_bfloat16*)(ws + WB_OFF);
    __hip_bfloat16* Wfcb  = (__hip_bfloat16*)(ws + WFC_OFF);
    __hip_bfloat16* hs    = (__hip_bfloat16*)(ws + HS_OFF);
    __hip_bfloat16* hzero = (__hip_bfloat16*)(ws + ST_OFF);
    float*          cbuf  = (float*)(ws + ST_OFF + HZ_BYTES);
    unsigned*       bar   = (unsigned*)(ws + ST_OFF + HZ_BYTES + C_BYTES);
    __hip_bfloat16* Gx    = (__hip_bfloat16*)(ws + GX_OFF);
    __hip_bfloat16* xb    = (__hip_bfloat16*)(ws + GX_OFF);   // persist-mode x bf16

    // persist mode needs xb (32 MiB); fallback needs Gx chunks at same offset
    const size_t XB_BYTES = (size_t)BATCH * SEQ * IND * 2;
    const int persist = (GX_OFF + XB_BYTES <= ws_size);
    int T_CHUNK = 1;
    if (!persist) {
        const size_t GX_STEP = (size_t)BATCH * NG * 2;   // 256 KiB per step
        const int fopts[3] = {8, 2, 1};
        for (int i = 0; i < 3; i++) {
            if (GX_OFF + (size_t)fopts[i] * GX_STEP <= ws_size) {
                T_CHUNK = fopts[i]; break;
            }
        }
    }

    // one-time weight conversion fp32 -> bf16
    cvt_f32_bf16<<<2048, 256, 0, stream>>>(Wf, Wb + 0 * (size_t)WG_ELEMS, WG_ELEMS);
    cvt_f32_bf16<<<2048, 256, 0, stream>>>(Wi, Wb + 1 * (size_t)WG_ELEMS, WG_ELEMS);
    cvt_f32_bf16<<<2048, 256, 0, stream>>>(Wc, Wb + 2 * (size_t)WG_ELEMS, WG_ELEMS);
    cvt_f32_bf16<<<2048, 256, 0, stream>>>(Wo, Wb + 3 * (size_t)WG_ELEMS, WG_ELEMS);
    cvt_f32_bf16<<<1024, 256, 0, stream>>>(Wfc, Wfcb, HD * HD);

    // zero hzero, c, barrier state (ws poisoned 0xAA every launch)
    hipMemsetAsync(ws + ST_OFF, 0, ST_BYTES, stream);

    if (persist) {
        // x fp32 -> bf16 (16 Mi elements)
        cvt_f32_bf16<<<(BATCH * SEQ * IND) / 1024, 256, 0, stream>>>(
            x, xb, BATCH * SEQ * IND);
        // single fused launch: recurrence + in-block Gx production
        lstm_persist<<<PBLK, 512, 0, stream>>>(
            Wb, xb, bf_, bi_, bc_, bo_, 0, SEQ, hzero, cbuf, hs, bar);
    } else {
        for (int t0 = 0; t0 < SEQ; t0 += T_CHUNK) {
            gemm_gx<<<T_CHUNK * 8, 256, 0, stream>>>(
                x, Wb, bf_, bi_, bc_, bo_, Gx, t0);
            for (int t = t0; t < t0 + T_CHUNK; t++) {
                const __hip_bfloat16* gx_t = Gx + (size_t)(t - t0) * BATCH * NG;
                lstm_step<<<16, 256, 0, stream>>>(gx_t, t, Wb, hzero, cbuf, hs);
            }
        }
    }

    gemm_fc<<<1024, 256, 0, stream>>>(hs, Wfcb, bfc, out);
}

// Round 7
// 2801.906 us; speedup vs baseline: 1.2626x; 1.2626x over previous
//
#include <hip/hip_runtime.h>
#include <hip/hip_bf16.h>

#define BATCH 32
#define SEQ   512
#define IND   1024
#define HD    1024
#define ZD    2048   // IN + H
#define NG    4096   // 4*H
#define WG_ELEMS (1024 * 2048)   // elements per gate weight matrix
#define PBLK 128                 // consumer grid size (producers: PBLK..2*PBLK)

typedef short  shortx8 __attribute__((ext_vector_type(8)));
typedef float  floatx4 __attribute__((ext_vector_type(4)));

#define MFMA16(a, b, c) __builtin_amdgcn_mfma_f32_16x16x32_bf16((a), (b), (c), 0, 0, 0)

__device__ __forceinline__ float sigmoidf_(float x) {
    return 1.0f / (1.0f + __expf(-x));
}
__device__ __forceinline__ float tanhf_(float x) {
    return 1.0f - 2.0f / (__expf(2.0f * x) + 1.0f);
}

__device__ __forceinline__ short bf16s(float x) {
    __hip_bfloat16 h = __float2bfloat16(x);
    return *reinterpret_cast<short*>(&h);
}

__device__ __forceinline__ float bf2f(unsigned short u) {
    unsigned v = ((unsigned)u) << 16;
    float f;
    __builtin_memcpy(&f, &v, 4);
    return f;
}

__device__ __forceinline__ shortx8 cvt8(const float* __restrict__ p) {
    float4 v0 = *(const float4*)p;
    float4 v1 = *(const float4*)(p + 4);
    shortx8 r;
    r[0] = bf16s(v0.x); r[1] = bf16s(v0.y); r[2] = bf16s(v0.z); r[3] = bf16s(v0.w);
    r[4] = bf16s(v1.x); r[5] = bf16s(v1.y); r[6] = bf16s(v1.z); r[7] = bf16s(v1.w);
    return r;
}

// ---------------------------------------------------------------------------
// fp32 -> bf16 weight conversion (one-time per launch). n % 4 == 0.
// ---------------------------------------------------------------------------
__global__ __launch_bounds__(256) void cvt_f32_bf16(
    const float* __restrict__ src, __hip_bfloat16* __restrict__ dst, int n)
{
    int i = (blockIdx.x * 256 + threadIdx.x) * 4;
    if (i < n) {
        float4 v = *(const float4*)(src + i);
        dst[i + 0] = __float2bfloat16(v.x);
        dst[i + 1] = __float2bfloat16(v.y);
        dst[i + 2] = __float2bfloat16(v.z);
        dst[i + 3] = __float2bfloat16(v.w);
    }
}

// ---------------------------------------------------------------------------
// Kernel 1 (FALLBACK only): x-part gate pre-activations for a chunk of T
// steps. Gx[(t-t0)*B + b][g*1024+j] = sum_k x[b][t][k]*Wg[j][1024+k] + bias.
// grid = T*8 blocks of 256.
// ---------------------------------------------------------------------------
__global__ __launch_bounds__(256) void gemm_gx(
    const float* __restrict__ x,
    const __hip_bfloat16* __restrict__ Wb,     // [4][1024][2048] bf16
    const float* __restrict__ bf_, const float* __restrict__ bi_,
    const float* __restrict__ bc_, const float* __restrict__ bo_,
    __hip_bfloat16* __restrict__ Gx, const int t0)
{
    const int wave = (blockIdx.x << 2) + (threadIdx.x >> 6);
    const int mt = wave >> 6;
    const int nt = wave & 63;
    const int lane = threadIdx.x & 63;
    const int quad = lane >> 4;
    const int l16  = lane & 15;
    const int m0 = mt << 6;
    const int n0 = nt << 6;
    const int g  = n0 >> 10;
    const __hip_bfloat16* Wg = Wb + (size_t)g * WG_ELEMS;
    const float* bg = (g == 0) ? bf_ : (g == 1) ? bi_ : (g == 2) ? bc_ : bo_;
    const int j0 = n0 & 1023;

    floatx4 acc[4][4];
#pragma unroll
    for (int i = 0; i < 4; i++)
#pragma unroll
        for (int j = 0; j < 4; j++) acc[i][j] = (floatx4)(0.0f);

    const float* arow[4];
    const __hip_bfloat16* brow[4];
#pragma unroll
    for (int i = 0; i < 4; i++) {
        const int r = m0 + i * 16 + l16;
        const int t = t0 + (r >> 5);
        const int b = r & 31;
        arow[i] = x + ((size_t)b * SEQ + t) * IND + quad * 8;
    }
#pragma unroll
    for (int j = 0; j < 4; j++)
        brow[j] = Wg + (size_t)(j0 + j * 16 + l16) * ZD + HD + quad * 8;

    for (int k0 = 0; k0 < IND; k0 += 32) {
        shortx8 a[4], b[4];
#pragma unroll
        for (int i = 0; i < 4; i++) a[i] = cvt8(arow[i] + k0);
#pragma unroll
        for (int j = 0; j < 4; j++) b[j] = *(const shortx8*)(brow[j] + k0);
#pragma unroll
        for (int i = 0; i < 4; i++)
#pragma unroll
            for (int j = 0; j < 4; j++)
                acc[i][j] = MFMA16(a[i], b[j], acc[i][j]);
    }

#pragma unroll
    for (int j = 0; j < 4; j++) {
        const int n  = n0 + j * 16 + l16;
        const int jj = j0 + j * 16 + l16;
        const float bias = bg[jj];
#pragma unroll
        for (int i = 0; i < 4; i++) {
#pragma unroll
            for (int r = 0; r < 4; r++) {
                const int row = m0 + i * 16 + quad * 4 + r;
                Gx[(size_t)row * NG + n] = __float2bfloat16(acc[i][j][r] + bias);
            }
        }
    }
}

// ---------------------------------------------------------------------------
// Kernel 2 (FALLBACK, small-ws path): one LSTM time step, hs-direct h I/O.
// ---------------------------------------------------------------------------
__global__ __launch_bounds__(256) void lstm_step(
    const __hip_bfloat16* __restrict__ gx,
    const int t,
    const __hip_bfloat16* __restrict__ Wb,
    const __hip_bfloat16* __restrict__ hzero,  // [B][H] zeros
    float* __restrict__ c,
    __hip_bfloat16* __restrict__ hs)           // [B][S][H]
{
    const int jt = (blockIdx.x << 2) + (threadIdx.x >> 6);
    const int lane = threadIdx.x & 63;
    const int quad = lane >> 4;
    const int l16  = lane & 15;
    const int j0   = jt << 4;

    const __hip_bfloat16* hb;
    size_t rstride;
    if (t == 0) { hb = hzero; rstride = HD; }
    else        { hb = hs + (size_t)(t - 1) * HD; rstride = (size_t)SEQ * HD; }

    const __hip_bfloat16* wrow[4];
#pragma unroll
    for (int g = 0; g < 4; g++)
        wrow[g] = Wb + (size_t)g * WG_ELEMS + (size_t)(j0 + l16) * ZD + quad * 8;

    const __hip_bfloat16* hrow0 = hb + (size_t)l16 * rstride + quad * 8;
    const __hip_bfloat16* hrow1 = hb + (size_t)(16 + l16) * rstride + quad * 8;

    floatx4 acc[4][2];
#pragma unroll
    for (int g = 0; g < 4; g++) { acc[g][0] = (floatx4)(0.0f); acc[g][1] = (floatx4)(0.0f); }

    for (int k0 = 0; k0 < HD; k0 += 32) {
        shortx8 a0 = *(const shortx8*)(hrow0 + k0);
        shortx8 a1 = *(const shortx8*)(hrow1 + k0);
#pragma unroll
        for (int g = 0; g < 4; g++) {
            shortx8 bfrag = *(const shortx8*)(wrow[g] + k0);
            acc[g][0] = MFMA16(a0, bfrag, acc[g][0]);
            acc[g][1] = MFMA16(a1, bfrag, acc[g][1]);
        }
    }

    const int j = j0 + l16;
#pragma unroll
    for (int i = 0; i < 2; i++) {
#pragma unroll
        for (int r = 0; r < 4; r++) {
            const int bb = i * 16 + quad * 4 + r;
            const size_t gbase = (size_t)bb * NG + j;
            const float fp = acc[0][i][r] + __bfloat162float(gx[gbase + 0 * HD]);
            const float ip = acc[1][i][r] + __bfloat162float(gx[gbase + 1 * HD]);
            const float cp = acc[2][i][r] + __bfloat162float(gx[gbase + 2 * HD]);
            const float op = acc[3][i][r] + __bfloat162float(gx[gbase + 3 * HD]);
            const float fg = sigmoidf_(fp);
            const float ig = sigmoidf_(ip);
            const float cg = tanhf_(cp);
            const float og = sigmoidf_(op);
            const size_t ci = (size_t)bb * HD + j;
            const float cnew = ig * cg + fg * c[ci];
            const float hnew = og * tanhf_(cnew);
            c[ci] = cnew;
            hs[((size_t)bb * SEQ + t) * HD + j] = __float2bfloat16(hnew);
        }
    }
}

// ---------------------------------------------------------------------------
// Kernel 2' (FAST path): persistent recurrence + CONCURRENT Gx producers, v9.
//
// Grid = 256 blocks x 256 threads (one per CU, all co-resident):
//   blocks 0..127 (CONSUMERS): v7 structure verbatim — wave (wm=batch-half,
//     wk=K-half) computes both 16-col tiles of h@Wh^T over K=512 from global
//     hs[t-1]; 2-panel LDS reduce; pointwise; gx prefetched 1 step ahead;
//     distributed arrive-flag device barrier (relaxed sc1, parallel poll).
//   blocks 128..255 (PRODUCERS): compute the ENTIRE Gx array with the proven
//     gemm_gx 64x64 tile code (bias folded in) on SEPARATE CUs — v8's lesson:
//     producer work on a consumer CU contends for the same L1/TA port; on its
//     own CU it's free. Output via packed-u32 relaxed sc1 stores (coherence-
//     point visible, v5 mechanism), vmcnt(0) drain, then a +1 on the per-
//      64-row ready counter gcnt[mt] (64 tiles each). Task order: wave w takes
//     tiles tau = w + 512*i -> mt 0..7 complete in the first round (~5us);
//     producers (~450us total) run ~5x faster than consumers consume.
// Consumers poll gcnt[(t+1)>>1] (register-cached, one agent load every other
// step) before the gx prefetch. Producers never wait on anyone -> deadlock-
// free; consumers spin with s_sleep if ever ahead (only plausible at t=0).
// ---------------------------------------------------------------------------
__global__ __launch_bounds__(256, 1) void lstm_persist(
    const __hip_bfloat16* __restrict__ Wb,     // [4][1024][2048] bf16
    const float* __restrict__ x,               // [B][S][IND] fp32
    __hip_bfloat16* __restrict__ Gx,           // [S*B][NG] bf16 (full)
    const float* __restrict__ bf_, const float* __restrict__ bi_,
    const float* __restrict__ bc_, const float* __restrict__ bo_,
    const int T,
    const __hip_bfloat16* __restrict__ hzero,  // [B][H] zeros
    float* __restrict__ c_ws,                  // [PBLK*256] fp32
    __hip_bfloat16* __restrict__ hs,           // [B][S][H] bf16
    unsigned* __restrict__ bar)  // [0..127]*16: arrive slots; +2048: gcnt[256]*16
{
    __shared__ float accf[2 * 1168];

    const int tid  = threadIdx.x;
    const int blk  = blockIdx.x;
    const int wv   = tid >> 6;
    const int lane = tid & 63;
    const int quad = lane >> 4;
    const int l16  = lane & 15;
    unsigned* gcnt = bar + 2048;

    if (blk >= PBLK) {
        // ========================= PRODUCER =========================
        const int pw = (blk - PBLK) * 4 + wv;   // 0..511
        const int nt = pw & 63;                  // fixed col-tile (W stays L2-hot)
        const int n0 = nt << 6;
        const int g  = n0 >> 10;
        const __hip_bfloat16* Wg = Wb + (size_t)g * WG_ELEMS;
        const float* bg = (g == 0) ? bf_ : (g == 1) ? bi_ : (g == 2) ? bc_ : bo_;
        const int j0 = n0 & 1023;

        const __hip_bfloat16* brow[4];
#pragma unroll
        for (int j = 0; j < 4; j++)
            brow[j] = Wg + (size_t)(j0 + j * 16 + l16) * ZD + HD + quad * 8;

        float bias[4];
#pragma unroll
        for (int j = 0; j < 4; j++) bias[j] = bg[j0 + j * 16 + l16];

        for (int it = 0; it < 32; it++) {
            const int mt = (pw >> 6) + 8 * it;   // rows [mt*64, mt*64+64) = t-pair
            const int m0 = mt << 6;

            floatx4 acc[4][4];
#pragma unroll
            for (int i = 0; i < 4; i++)
#pragma unroll
                for (int j = 0; j < 4; j++) acc[i][j] = (floatx4)(0.0f);

            const float* arow[4];
#pragma unroll
            for (int i = 0; i < 4; i++) {
                const int r = m0 + i * 16 + l16;
                const int t = r >> 5;
                const int b = r & 31;
                arow[i] = x + ((size_t)b * SEQ + t) * IND + quad * 8;
            }

            for (int k0 = 0; k0 < IND; k0 += 32) {
                shortx8 a[4], b[4];
#pragma unroll
                for (int i = 0; i < 4; i++) a[i] = cvt8(arow[i] + k0);
#pragma unroll
                for (int j = 0; j < 4; j++) b[j] = *(const shortx8*)(brow[j] + k0);
#pragma unroll
                for (int i = 0; i < 4; i++)
#pragma unroll
                    for (int j = 0; j < 4; j++)
                        acc[i][j] = MFMA16(a[i], b[j], acc[i][j]);
            }

            // epilogue: packed-u32 relaxed sc1 stores (coherence-point visible)
#pragma unroll
            for (int j = 0; j < 4; j++) {
                const int n = n0 + j * 16 + l16;
#pragma unroll
                for (int i = 0; i < 4; i++) {
#pragma unroll
                    for (int r = 0; r < 4; r++) {
                        const int row = m0 + i * 16 + quad * 4 + r;
                        const float v = acc[i][j][r] + bias[j];
                        const unsigned my = (unsigned)(unsigned short)bf16s(v);
                        const unsigned nb = (unsigned)__shfl_xor((int)my, 1);
                        if ((l16 & 1) == 0) {
                            unsigned* dst = (unsigned*)(Gx + (size_t)row * NG + n);
                            __hip_atomic_store(dst, my | (nb << 16),
                                               __ATOMIC_RELAXED,
                                               __HIP_MEMORY_SCOPE_AGENT);
                        }
                    }
                }
            }
            // drain sc1 data stores to the coherence point, then signal
            asm volatile("s_waitcnt vmcnt(0)" ::: "memory");
            if (lane == 0)
                __hip_atomic_fetch_add(gcnt + mt * 16, 1u,
                                       __ATOMIC_RELAXED, __HIP_MEMORY_SCOPE_AGENT);
        }
        return;
    }

    // ========================= CONSUMER (v7) =========================
    const int wm = wv & 1;           // batch-half tile
    const int wk = wv >> 1;          // K-half

    shortx8 Bfrag[2][16];
#pragma unroll
    for (int ct = 0; ct < 2; ct++) {
        const int lc = ct * 16 + l16;
        const int jj = lc >> 2, g = lc & 3;
        const __hip_bfloat16* wr =
            Wb + (size_t)g * WG_ELEMS + (size_t)(blk * 8 + jj) * ZD + wk * 512 + quad * 8;
#pragma unroll
        for (int ks = 0; ks < 16; ks++)
            Bfrag[ct][ks] = *(const shortx8*)(wr + ks * 32);
    }

    const int pjj = tid & 7;
    const int pb  = tid >> 3;
    const int pj  = blk * 8 + pjj;
    float creg = c_ws[blk * 256 + tid];

    // prologue: wait for Gx rows of t=0 (mt 0), then load gx[0]
    while (__hip_atomic_load(gcnt, __ATOMIC_RELAXED,
                             __HIP_MEMORY_SCOPE_AGENT) < 64)
        __builtin_amdgcn_s_sleep(1);
    asm volatile("" ::: "memory");
    __builtin_amdgcn_sched_barrier(0);

    unsigned short gxr0, gxr1, gxr2, gxr3;
    {
        const __hip_bfloat16* gx = Gx + (size_t)pb * NG + pj;
        gxr0 = *(const unsigned short*)(gx + 0 * HD);
        gxr1 = *(const unsigned short*)(gx + 1 * HD);
        gxr2 = *(const unsigned short*)(gx + 2 * HD);
        gxr3 = *(const unsigned short*)(gx + 3 * HD);
    }
    int mt_ok = 0;

    for (int tt = 0; tt < T; tt++) {
        const int t = tt;
        const __hip_bfloat16* hb;
        size_t rstride;
        if (t == 0) { hb = hzero; rstride = HD; }
        else        { hb = hs + (size_t)(t - 1) * HD; rstride = (size_t)SEQ * HD; }

        // poll ready for next step's Gx rows (register-cached, 1 load / 2 steps)
        unsigned short ngxr0 = 0, ngxr1 = 0, ngxr2 = 0, ngxr3 = 0;
        if (tt + 1 < T) {
            const int mtn = (tt + 1) >> 1;
            if (mtn > mt_ok) {
                while (__hip_atomic_load(gcnt + mtn * 16, __ATOMIC_RELAXED,
                                         __HIP_MEMORY_SCOPE_AGENT) < 64)
                    __builtin_amdgcn_s_sleep(1);
                mt_ok = mtn;
                asm volatile("" ::: "memory");
                __builtin_amdgcn_sched_barrier(0);
            }
            const __hip_bfloat16* gx1 = Gx + ((size_t)(tt + 1) * BATCH + pb) * NG + pj;
            ngxr0 = *(const unsigned short*)(gx1 + 0 * HD);
            ngxr1 = *(const unsigned short*)(gx1 + 1 * HD);
            ngxr2 = *(const unsigned short*)(gx1 + 2 * HD);
            ngxr3 = *(const unsigned short*)(gx1 + 3 * HD);
        }

        // h @ Wh^T : one A-frag stream feeds BOTH col-tile chains
        const __hip_bfloat16* arow =
            hb + (size_t)(wm * 16 + l16) * rstride + wk * 512 + quad * 8;
        floatx4 acc0 = (floatx4)(0.0f), acc1 = (floatx4)(0.0f);
#pragma unroll
        for (int ks = 0; ks < 16; ks++) {
            shortx8 av = *(const shortx8*)(arow + ks * 32);
            acc0 = MFMA16(av, Bfrag[0][ks], acc0);
            acc1 = MFMA16(av, Bfrag[1][ks], acc1);
        }

        // acc -> LDS [wk][col][b], stride 36 floats (16B-aligned)
        {
            const int b0 = wm * 16 + quad * 4;
            *(floatx4*)(accf + wk * 1168 + (l16)      * 36 + b0) = acc0;
            *(floatx4*)(accf + wk * 1168 + (16 + l16) * 36 + b0) = acc1;
        }
        __syncthreads();

        // pointwise for (pb, pjj); c lives in a register across the launch
        {
            const int i0 = (pjj * 4 + 0) * 36 + pb;
            const int i1 = (pjj * 4 + 1) * 36 + pb;
            const int i2 = (pjj * 4 + 2) * 36 + pb;
            const int i3 = (pjj * 4 + 3) * 36 + pb;
            const float fp = accf[i0] + accf[1168 + i0] + bf2f(gxr0);
            const float ip = accf[i1] + accf[1168 + i1] + bf2f(gxr1);
            const float cp = accf[i2] + accf[1168 + i2] + bf2f(gxr2);
            const float op = accf[i3] + accf[1168 + i3] + bf2f(gxr3);
            const float fg = sigmoidf_(fp);
            const float ig = sigmoidf_(ip);
            const float cg = tanhf_(cp);
            const float og = sigmoidf_(op);
            creg = ig * cg + fg * creg;
            const float hnew = og * tanhf_(creg);

            // packed-u32 relaxed agent store (sc1 => coherence-point visible)
            const unsigned my = (unsigned)(unsigned short)bf16s(hnew);
            const unsigned nb = (unsigned)__shfl_xor((int)my, 1);
            if ((tid & 1) == 0) {
                unsigned* dst = (unsigned*)(hs + ((size_t)pb * SEQ + t) * HD + pj);
                const unsigned packed = my | (nb << 16);
                __hip_atomic_store(dst, packed, __ATOMIC_RELAXED,
                                   __HIP_MEMORY_SCOPE_AGENT);
            }
        }

        // device barrier among CONSUMER blocks (not needed after last step)
        if (tt < T - 1) {
            __syncthreads();   // per-wave s_waitcnt vmcnt(0): sc1 stores at IF
            const unsigned epoch = (unsigned)(tt + 1);
            if (wv == 0) {
                if (lane == 0) {
                    __hip_atomic_store(bar + blk * 16, epoch, __ATOMIC_RELAXED,
                                       __HIP_MEMORY_SCOPE_AGENT);
                }
                // parallel poll: lane L watches slots L and L+64 (sticky)
                unsigned* p0 = bar + lane * 16;
                unsigned* p1 = bar + (64 + lane) * 16;
                bool d0 = false, d1 = false;
                while (true) {
                    if (!d0) d0 = (__hip_atomic_load(p0, __ATOMIC_RELAXED,
                                       __HIP_MEMORY_SCOPE_AGENT) >= epoch);
                    if (!d1) d1 = (__hip_atomic_load(p1, __ATOMIC_RELAXED,
                                       __HIP_MEMORY_SCOPE_AGENT) >= epoch);
                    if (__all(d0 && d1)) break;
                    __builtin_amdgcn_s_sleep(1);
                }
                asm volatile("" ::: "memory");
                __builtin_amdgcn_sched_barrier(0);
            }
            __syncthreads();
        }

        gxr0 = ngxr0; gxr1 = ngxr1; gxr2 = ngxr2; gxr3 = ngxr3;
    }

    c_ws[blk * 256 + tid] = creg;
}

// ---------------------------------------------------------------------------
// Kernel 3: out[r][n] = sum_k hs[r][k] * Wfc[n][k] + bfc[n]   (fp32 out)
// ---------------------------------------------------------------------------
__global__ __launch_bounds__(256) void gemm_fc(
    const __hip_bfloat16* __restrict__ hs,
    const __hip_bfloat16* __restrict__ Wfcb,
    const float* __restrict__ bfc,
    float* __restrict__ out)
{
    const int wave = (blockIdx.x << 2) + (threadIdx.x >> 6);
    const int mt = wave >> 4;
    const int nt = wave & 15;
    const int lane = threadIdx.x & 63;
    const int quad = lane >> 4;
    const int l16  = lane & 15;
    const int m0 = mt << 6;
    const int n0 = nt << 6;

    floatx4 acc[4][4];
#pragma unroll
    for (int i = 0; i < 4; i++)
#pragma unroll
        for (int j = 0; j < 4; j++) acc[i][j] = (floatx4)(0.0f);

    const __hip_bfloat16* arow[4];
    const __hip_bfloat16* brow[4];
#pragma unroll
    for (int i = 0; i < 4; i++)
        arow[i] = hs + (size_t)(m0 + i * 16 + l16) * HD + quad * 8;
#pragma unroll
    for (int j = 0; j < 4; j++)
        brow[j] = Wfcb + (size_t)(n0 + j * 16 + l16) * HD + quad * 8;

    for (int k0 = 0; k0 < HD; k0 += 32) {
        shortx8 a[4], b[4];
#pragma unroll
        for (int i = 0; i < 4; i++) a[i] = *(const shortx8*)(arow[i] + k0);
#pragma unroll
        for (int j = 0; j < 4; j++) b[j] = *(const shortx8*)(brow[j] + k0);
#pragma unroll
        for (int i = 0; i < 4; i++)
#pragma unroll
            for (int j = 0; j < 4; j++)
                acc[i][j] = MFMA16(a[i], b[j], acc[i][j]);
    }

#pragma unroll
    for (int j = 0; j < 4; j++) {
        const int n = n0 + j * 16 + l16;
        const float bias = bfc[n];
#pragma unroll
        for (int i = 0; i < 4; i++) {
#pragma unroll
            for (int r = 0; r < 4; r++) {
                const int row = m0 + i * 16 + quad * 4 + r;
                out[(size_t)row * 1024 + n] = acc[i][j][r] + bias;
            }
        }
    }
}

// ---------------------------------------------------------------------------
extern "C" void kernel_launch(void* const* d_in, const int* in_sizes, int n_in,
                              void* d_out, int out_size, void* d_ws, size_t ws_size,
                              hipStream_t stream) {
    const float* x   = (const float*)d_in[0];
    const float* Wf  = (const float*)d_in[1];
    const float* bf_ = (const float*)d_in[2];
    const float* Wi  = (const float*)d_in[3];
    const float* bi_ = (const float*)d_in[4];
    const float* Wc  = (const float*)d_in[5];
    const float* bc_ = (const float*)d_in[6];
    const float* Wo  = (const float*)d_in[7];
    const float* bo_ = (const float*)d_in[8];
    const float* Wfc = (const float*)d_in[9];
    const float* bfc = (const float*)d_in[10];
    float* out = (float*)d_out;

    // ---- ws layout (bytes) ----
    char* ws = (char*)d_ws;
    const size_t WB_OFF  = 0;                                          // 16 MiB
    const size_t WFC_OFF = (size_t)4 * WG_ELEMS * 2;                   // +2 MiB
    const size_t HS_OFF  = WFC_OFF + (size_t)HD * HD * 2;              // +32 MiB
    const size_t ST_OFF  = HS_OFF + (size_t)BATCH * SEQ * HD * 2;
    const size_t HZ_BYTES  = (size_t)BATCH * HD * 2;                   // 64 KiB
    const size_t C_BYTES   = (size_t)PBLK * 256 * 4;                   // 128 KiB
    const size_t BAR_BYTES = 128 * 64 + 256 * 64;  // arrive slots + gcnt[256]
    const size_t ST_BYTES  = HZ_BYTES + C_BYTES + BAR_BYTES;
    const size_t GX_OFF  = ST_OFF + ST_BYTES;

    __hip_bfloat16* Wb    = (__hip_bfloat16*)(ws + WB_OFF);
    __hip_bfloat16* Wfcb  = (__hip_bfloat16*)(ws + WFC_OFF);
    __hip_bfloat16* hs    = (__hip_bfloat16*)(ws + HS_OFF);
    __hip_bfloat16* hzero = (__hip_bfloat16*)(ws + ST_OFF);
    float*          cbuf  = (float*)(ws + ST_OFF + HZ_BYTES);
    unsigned*       bar   = (unsigned*)(ws + ST_OFF + HZ_BYTES + C_BYTES);
    __hip_bfloat16* Gx    = (__hip_bfloat16*)(ws + GX_OFF);

    // fast path needs the full Gx array (128 MiB)
    const size_t GX_FULL = (size_t)SEQ * BATCH * NG * 2;
    const int persist = (GX_OFF + GX_FULL <= ws_size);
    int T_CHUNK = 1;
    if (!persist) {
        const size_t GX_STEP = (size_t)BATCH * NG * 2;   // 256 KiB per step
        const int fopts[3] = {8, 2, 1};
        for (int i = 0; i < 3; i++) {
            if (GX_OFF + (size_t)fopts[i] * GX_STEP <= ws_size) {
                T_CHUNK = fopts[i]; break;
            }
        }
    }

    // one-time weight conversion fp32 -> bf16
    cvt_f32_bf16<<<2048, 256, 0, stream>>>(Wf, Wb + 0 * (size_t)WG_ELEMS, WG_ELEMS);
    cvt_f32_bf16<<<2048, 256, 0, stream>>>(Wi, Wb + 1 * (size_t)WG_ELEMS, WG_ELEMS);
    cvt_f32_bf16<<<2048, 256, 0, stream>>>(Wc, Wb + 2 * (size_t)WG_ELEMS, WG_ELEMS);
    cvt_f32_bf16<<<2048, 256, 0, stream>>>(Wo, Wb + 3 * (size_t)WG_ELEMS, WG_ELEMS);
    cvt_f32_bf16<<<1024, 256, 0, stream>>>(Wfc, Wfcb, HD * HD);

    // zero hzero, c, barrier + ready-counter state (ws poisoned every launch)
    hipMemsetAsync(ws + ST_OFF, 0, ST_BYTES, stream);

    if (persist) {
        // single launch: 128 consumer blocks + 128 producer blocks (256 CUs)
        lstm_persist<<<2 * PBLK, 256, 0, stream>>>(
            Wb, x, Gx, bf_, bi_, bc_, bo_, SEQ, hzero, cbuf, hs, bar);
    } else {
        for (int t0 = 0; t0 < SEQ; t0 += T_CHUNK) {
            gemm_gx<<<T_CHUNK * 8, 256, 0, stream>>>(
                x, Wb, bf_, bi_, bc_, bo_, Gx, t0);
            for (int t = t0; t < t0 + T_CHUNK; t++) {
                const __hip_bfloat16* gx_t = Gx + (size_t)(t - t0) * BATCH * NG;
                lstm_step<<<16, 256, 0, stream>>>(gx_t, t, Wb, hzero, cbuf, hs);
            }
        }
    }

    gemm_fc<<<1024, 256, 0, stream>>>(hs, Wfcb, bfc, out);
}

// Round 8
// 2754.205 us; speedup vs baseline: 1.2845x; 1.0173x over previous
//
#include <hip/hip_runtime.h>
#include <hip/hip_bf16.h>

#define BATCH 32
#define SEQ   512
#define IND   1024
#define HD    1024
#define ZD    2048   // IN + H
#define NG    4096   // 4*H
#define WG_ELEMS (1024 * 2048)   // elements per gate weight matrix
#define PBLK 128                 // consumer grid size (producers: PBLK..2*PBLK)

typedef short  shortx8 __attribute__((ext_vector_type(8)));
typedef float  floatx4 __attribute__((ext_vector_type(4)));

#define MFMA16(a, b, c) __builtin_amdgcn_mfma_f32_16x16x32_bf16((a), (b), (c), 0, 0, 0)

__device__ __forceinline__ float sigmoidf_(float x) {
    return 1.0f / (1.0f + __expf(-x));
}
__device__ __forceinline__ float tanhf_(float x) {
    return 1.0f - 2.0f / (__expf(2.0f * x) + 1.0f);
}

__device__ __forceinline__ short bf16s(float x) {
    __hip_bfloat16 h = __float2bfloat16(x);
    return *reinterpret_cast<short*>(&h);
}

__device__ __forceinline__ float bf2f(unsigned short u) {
    unsigned v = ((unsigned)u) << 16;
    float f;
    __builtin_memcpy(&f, &v, 4);
    return f;
}

__device__ __forceinline__ shortx8 cvt8(const float* __restrict__ p) {
    float4 v0 = *(const float4*)p;
    float4 v1 = *(const float4*)(p + 4);
    shortx8 r;
    r[0] = bf16s(v0.x); r[1] = bf16s(v0.y); r[2] = bf16s(v0.z); r[3] = bf16s(v0.w);
    r[4] = bf16s(v1.x); r[5] = bf16s(v1.y); r[6] = bf16s(v1.z); r[7] = bf16s(v1.w);
    return r;
}

// ---------------------------------------------------------------------------
// fp32 -> bf16 weight conversion (one-time per launch). n % 4 == 0.
// ---------------------------------------------------------------------------
__global__ __launch_bounds__(256) void cvt_f32_bf16(
    const float* __restrict__ src, __hip_bfloat16* __restrict__ dst, int n)
{
    int i = (blockIdx.x * 256 + threadIdx.x) * 4;
    if (i < n) {
        float4 v = *(const float4*)(src + i);
        dst[i + 0] = __float2bfloat16(v.x);
        dst[i + 1] = __float2bfloat16(v.y);
        dst[i + 2] = __float2bfloat16(v.z);
        dst[i + 3] = __float2bfloat16(v.w);
    }
}

// ---------------------------------------------------------------------------
// Kernel 1 (FALLBACK only): x-part gate pre-activations for a chunk of T
// steps. Gx[(t-t0)*B + b][g*1024+j] = sum_k x[b][t][k]*Wg[j][1024+k] + bias.
// grid = T*8 blocks of 256.
// ---------------------------------------------------------------------------
__global__ __launch_bounds__(256) void gemm_gx(
    const float* __restrict__ x,
    const __hip_bfloat16* __restrict__ Wb,     // [4][1024][2048] bf16
    const float* __restrict__ bf_, const float* __restrict__ bi_,
    const float* __restrict__ bc_, const float* __restrict__ bo_,
    __hip_bfloat16* __restrict__ Gx, const int t0)
{
    const int wave = (blockIdx.x << 2) + (threadIdx.x >> 6);
    const int mt = wave >> 6;
    const int nt = wave & 63;
    const int lane = threadIdx.x & 63;
    const int quad = lane >> 4;
    const int l16  = lane & 15;
    const int m0 = mt << 6;
    const int n0 = nt << 6;
    const int g  = n0 >> 10;
    const __hip_bfloat16* Wg = Wb + (size_t)g * WG_ELEMS;
    const float* bg = (g == 0) ? bf_ : (g == 1) ? bi_ : (g == 2) ? bc_ : bo_;
    const int j0 = n0 & 1023;

    floatx4 acc[4][4];
#pragma unroll
    for (int i = 0; i < 4; i++)
#pragma unroll
        for (int j = 0; j < 4; j++) acc[i][j] = (floatx4)(0.0f);

    const float* arow[4];
    const __hip_bfloat16* brow[4];
#pragma unroll
    for (int i = 0; i < 4; i++) {
        const int r = m0 + i * 16 + l16;
        const int t = t0 + (r >> 5);
        const int b = r & 31;
        arow[i] = x + ((size_t)b * SEQ + t) * IND + quad * 8;
    }
#pragma unroll
    for (int j = 0; j < 4; j++)
        brow[j] = Wg + (size_t)(j0 + j * 16 + l16) * ZD + HD + quad * 8;

    for (int k0 = 0; k0 < IND; k0 += 32) {
        shortx8 a[4], b[4];
#pragma unroll
        for (int i = 0; i < 4; i++) a[i] = cvt8(arow[i] + k0);
#pragma unroll
        for (int j = 0; j < 4; j++) b[j] = *(const shortx8*)(brow[j] + k0);
#pragma unroll
        for (int i = 0; i < 4; i++)
#pragma unroll
            for (int j = 0; j < 4; j++)
                acc[i][j] = MFMA16(a[i], b[j], acc[i][j]);
    }

#pragma unroll
    for (int j = 0; j < 4; j++) {
        const int n  = n0 + j * 16 + l16;
        const int jj = j0 + j * 16 + l16;
        const float bias = bg[jj];
#pragma unroll
        for (int i = 0; i < 4; i++) {
#pragma unroll
            for (int r = 0; r < 4; r++) {
                const int row = m0 + i * 16 + quad * 4 + r;
                Gx[(size_t)row * NG + n] = __float2bfloat16(acc[i][j][r] + bias);
            }
        }
    }
}

// ---------------------------------------------------------------------------
// Kernel 2 (FALLBACK, small-ws path): one LSTM time step, hs-direct h I/O.
// ---------------------------------------------------------------------------
__global__ __launch_bounds__(256) void lstm_step(
    const __hip_bfloat16* __restrict__ gx,
    const int t,
    const __hip_bfloat16* __restrict__ Wb,
    const __hip_bfloat16* __restrict__ hzero,  // [B][H] zeros
    float* __restrict__ c,
    __hip_bfloat16* __restrict__ hs)           // [B][S][H]
{
    const int jt = (blockIdx.x << 2) + (threadIdx.x >> 6);
    const int lane = threadIdx.x & 63;
    const int quad = lane >> 4;
    const int l16  = lane & 15;
    const int j0   = jt << 4;

    const __hip_bfloat16* hb;
    size_t rstride;
    if (t == 0) { hb = hzero; rstride = HD; }
    else        { hb = hs + (size_t)(t - 1) * HD; rstride = (size_t)SEQ * HD; }

    const __hip_bfloat16* wrow[4];
#pragma unroll
    for (int g = 0; g < 4; g++)
        wrow[g] = Wb + (size_t)g * WG_ELEMS + (size_t)(j0 + l16) * ZD + quad * 8;

    const __hip_bfloat16* hrow0 = hb + (size_t)l16 * rstride + quad * 8;
    const __hip_bfloat16* hrow1 = hb + (size_t)(16 + l16) * rstride + quad * 8;

    floatx4 acc[4][2];
#pragma unroll
    for (int g = 0; g < 4; g++) { acc[g][0] = (floatx4)(0.0f); acc[g][1] = (floatx4)(0.0f); }

    for (int k0 = 0; k0 < HD; k0 += 32) {
        shortx8 a0 = *(const shortx8*)(hrow0 + k0);
        shortx8 a1 = *(const shortx8*)(hrow1 + k0);
#pragma unroll
        for (int g = 0; g < 4; g++) {
            shortx8 bfrag = *(const shortx8*)(wrow[g] + k0);
            acc[g][0] = MFMA16(a0, bfrag, acc[g][0]);
            acc[g][1] = MFMA16(a1, bfrag, acc[g][1]);
        }
    }

    const int j = j0 + l16;
#pragma unroll
    for (int i = 0; i < 2; i++) {
#pragma unroll
        for (int r = 0; r < 4; r++) {
            const int bb = i * 16 + quad * 4 + r;
            const size_t gbase = (size_t)bb * NG + j;
            const float fp = acc[0][i][r] + __bfloat162float(gx[gbase + 0 * HD]);
            const float ip = acc[1][i][r] + __bfloat162float(gx[gbase + 1 * HD]);
            const float cp = acc[2][i][r] + __bfloat162float(gx[gbase + 2 * HD]);
            const float op = acc[3][i][r] + __bfloat162float(gx[gbase + 3 * HD]);
            const float fg = sigmoidf_(fp);
            const float ig = sigmoidf_(ip);
            const float cg = tanhf_(cp);
            const float og = sigmoidf_(op);
            const size_t ci = (size_t)bb * HD + j;
            const float cnew = ig * cg + fg * c[ci];
            const float hnew = og * tanhf_(cnew);
            c[ci] = cnew;
            hs[((size_t)bb * SEQ + t) * HD + j] = __float2bfloat16(hnew);
        }
    }
}

// ---------------------------------------------------------------------------
// Kernel 2' (FAST path): persistent recurrence + concurrent Gx + fused FC, v10.
//
// Grid = 256 blocks x 256 threads (one per CU, all co-resident):
//   blocks 0..127 (CONSUMERS): v7/v9 structure — wave (wm=batch-half,
//     wk=K-half) computes both 16-col tiles of h@Wh^T over K=512 from global
//     hs[t-1]; 2-panel LDS reduce; pointwise; gx prefetched 1 step ahead;
//     distributed arrive-flag device barrier (relaxed sc1, parallel poll).
//     v10: also signal a FINAL epoch T (=512) after the last step so FC
//     workers can gate the last t-chunk.
//   blocks 128..255 (PRODUCERS): phase 1 = full Gx array (gemm_gx tiles,
//     bias folded, packed-u32 relaxed sc1 stores, vmcnt drain, gcnt[mt]+1).
//     phase 2 (v10, NEW) = the FC GEMM out = hs @ Wfc^T + bfc, fused in:
//     wave task = fixed (fb = (pb&7)*4+wv, fnt = pb>>3) so all 16 col-tiles
//     of one batch live on ONE XCD (blk%8) -> hs rows fetched once per XCD L2.
//     t-chunk k (64 steps) gated on ALL consumer epochs >= (k+1)*64 via the
//     same lane-parallel flag poll. FC trickles along behind the recurrence;
//     only chunk 7 is a true tail (~40us). Host gemm_fc launch deleted.
// ---------------------------------------------------------------------------
__global__ __launch_bounds__(256, 1) void lstm_persist(
    const __hip_bfloat16* __restrict__ Wb,     // [4][1024][2048] bf16
    const float* __restrict__ x,               // [B][S][IND] fp32
    __hip_bfloat16* __restrict__ Gx,           // [S*B][NG] bf16 (full)
    const float* __restrict__ bf_, const float* __restrict__ bi_,
    const float* __restrict__ bc_, const float* __restrict__ bo_,
    const __hip_bfloat16* __restrict__ Wfcb,   // [1024][1024] bf16
    const float* __restrict__ bfc,
    float* __restrict__ out,                   // [B*S][1024] fp32
    const int T,
    const __hip_bfloat16* __restrict__ hzero,  // [B][H] zeros
    float* __restrict__ c_ws,                  // [PBLK*256] fp32
    __hip_bfloat16* __restrict__ hs,           // [B][S][H] bf16
    unsigned* __restrict__ bar)  // [0..127]*16: arrive slots; +2048: gcnt[256]*16
{
    __shared__ float accf[2 * 1168];

    const int tid  = threadIdx.x;
    const int blk  = blockIdx.x;
    const int wv   = tid >> 6;
    const int lane = tid & 63;
    const int quad = lane >> 4;
    const int l16  = lane & 15;
    unsigned* gcnt = bar + 2048;

    if (blk >= PBLK) {
        // ========================= PRODUCER =========================
        const int pb_ = blk - PBLK;              // 0..127
        const int pw = pb_ * 4 + wv;             // 0..511
        {
            const int nt = pw & 63;              // fixed col-tile (W stays L2-hot)
            const int n0 = nt << 6;
            const int g  = n0 >> 10;
            const __hip_bfloat16* Wg = Wb + (size_t)g * WG_ELEMS;
            const float* bg = (g == 0) ? bf_ : (g == 1) ? bi_ : (g == 2) ? bc_ : bo_;
            const int j0 = n0 & 1023;

            const __hip_bfloat16* brow[4];
#pragma unroll
            for (int j = 0; j < 4; j++)
                brow[j] = Wg + (size_t)(j0 + j * 16 + l16) * ZD + HD + quad * 8;

            float bias[4];
#pragma unroll
            for (int j = 0; j < 4; j++) bias[j] = bg[j0 + j * 16 + l16];

            for (int it = 0; it < 32; it++) {
                const int mt = (pw >> 6) + 8 * it;  // rows [mt*64, +64) = t-pair
                const int m0 = mt << 6;

                floatx4 acc[4][4];
#pragma unroll
                for (int i = 0; i < 4; i++)
#pragma unroll
                    for (int j = 0; j < 4; j++) acc[i][j] = (floatx4)(0.0f);

                const float* arow[4];
#pragma unroll
                for (int i = 0; i < 4; i++) {
                    const int r = m0 + i * 16 + l16;
                    const int t = r >> 5;
                    const int b = r & 31;
                    arow[i] = x + ((size_t)b * SEQ + t) * IND + quad * 8;
                }

                for (int k0 = 0; k0 < IND; k0 += 32) {
                    shortx8 a[4], b[4];
#pragma unroll
                    for (int i = 0; i < 4; i++) a[i] = cvt8(arow[i] + k0);
#pragma unroll
                    for (int j = 0; j < 4; j++) b[j] = *(const shortx8*)(brow[j] + k0);
#pragma unroll
                    for (int i = 0; i < 4; i++)
#pragma unroll
                        for (int j = 0; j < 4; j++)
                            acc[i][j] = MFMA16(a[i], b[j], acc[i][j]);
                }

                // packed-u32 relaxed sc1 stores (coherence-point visible)
#pragma unroll
                for (int j = 0; j < 4; j++) {
                    const int n = n0 + j * 16 + l16;
#pragma unroll
                    for (int i = 0; i < 4; i++) {
#pragma unroll
                        for (int r = 0; r < 4; r++) {
                            const int row = m0 + i * 16 + quad * 4 + r;
                            const float v = acc[i][j][r] + bias[j];
                            const unsigned my = (unsigned)(unsigned short)bf16s(v);
                            const unsigned nb = (unsigned)__shfl_xor((int)my, 1);
                            if ((l16 & 1) == 0) {
                                unsigned* dst = (unsigned*)(Gx + (size_t)row * NG + n);
                                __hip_atomic_store(dst, my | (nb << 16),
                                                   __ATOMIC_RELAXED,
                                                   __HIP_MEMORY_SCOPE_AGENT);
                            }
                        }
                    }
                }
                // drain sc1 data stores to the coherence point, then signal
                asm volatile("s_waitcnt vmcnt(0)" ::: "memory");
                if (lane == 0)
                    __hip_atomic_fetch_add(gcnt + mt * 16, 1u,
                                           __ATOMIC_RELAXED, __HIP_MEMORY_SCOPE_AGENT);
            }
        }

        // ---------------- FC phase: out = hs @ Wfc^T + bfc ----------------
        {
            const int fb  = (pb_ & 7) * 4 + wv;  // batch 0..31 (same-XCD group)
            const int fnt = pb_ >> 3;            // col-tile 0..15
            const int n0  = fnt << 6;

            const __hip_bfloat16* brow[4];
#pragma unroll
            for (int j = 0; j < 4; j++)
                brow[j] = Wfcb + (size_t)(n0 + j * 16 + l16) * HD + quad * 8;
            float biasf[4];
#pragma unroll
            for (int j = 0; j < 4; j++) biasf[j] = bfc[n0 + j * 16 + l16];

            for (int tc = 0; tc < 8; tc++) {
                // gate: all consumer epochs >= (tc+1)*64
                const unsigned need = (unsigned)((tc + 1) * 64);
                {
                    unsigned* p0 = bar + lane * 16;
                    unsigned* p1 = bar + (64 + lane) * 16;
                    bool d0 = false, d1 = false;
                    while (true) {
                        if (!d0) d0 = (__hip_atomic_load(p0, __ATOMIC_RELAXED,
                                           __HIP_MEMORY_SCOPE_AGENT) >= need);
                        if (!d1) d1 = (__hip_atomic_load(p1, __ATOMIC_RELAXED,
                                           __HIP_MEMORY_SCOPE_AGENT) >= need);
                        if (__all(d0 && d1)) break;
                        __builtin_amdgcn_s_sleep(8);
                    }
                    asm volatile("" ::: "memory");
                    __builtin_amdgcn_sched_barrier(0);
                }

                const int m0 = fb * SEQ + tc * 64;

                floatx4 acc[4][4];
#pragma unroll
                for (int i = 0; i < 4; i++)
#pragma unroll
                    for (int j = 0; j < 4; j++) acc[i][j] = (floatx4)(0.0f);

                const __hip_bfloat16* arow[4];
#pragma unroll
                for (int i = 0; i < 4; i++)
                    arow[i] = hs + (size_t)(m0 + i * 16 + l16) * HD + quad * 8;

                for (int k0 = 0; k0 < HD; k0 += 32) {
                    shortx8 a[4], b[4];
#pragma unroll
                    for (int i = 0; i < 4; i++) a[i] = *(const shortx8*)(arow[i] + k0);
#pragma unroll
                    for (int j = 0; j < 4; j++) b[j] = *(const shortx8*)(brow[j] + k0);
#pragma unroll
                    for (int i = 0; i < 4; i++)
#pragma unroll
                        for (int j = 0; j < 4; j++)
                            acc[i][j] = MFMA16(a[i], b[j], acc[i][j]);
                }

#pragma unroll
                for (int j = 0; j < 4; j++) {
                    const int n = n0 + j * 16 + l16;
#pragma unroll
                    for (int i = 0; i < 4; i++) {
#pragma unroll
                        for (int r = 0; r < 4; r++) {
                            const int row = m0 + i * 16 + quad * 4 + r;
                            out[(size_t)row * 1024 + n] = acc[i][j][r] + biasf[j];
                        }
                    }
                }
            }
        }
        return;
    }

    // ========================= CONSUMER (v7/v9) =========================
    const int wm = wv & 1;           // batch-half tile
    const int wk = wv >> 1;          // K-half

    shortx8 Bfrag[2][16];
#pragma unroll
    for (int ct = 0; ct < 2; ct++) {
        const int lc = ct * 16 + l16;
        const int jj = lc >> 2, g = lc & 3;
        const __hip_bfloat16* wr =
            Wb + (size_t)g * WG_ELEMS + (size_t)(blk * 8 + jj) * ZD + wk * 512 + quad * 8;
#pragma unroll
        for (int ks = 0; ks < 16; ks++)
            Bfrag[ct][ks] = *(const shortx8*)(wr + ks * 32);
    }

    const int pjj = tid & 7;
    const int pb  = tid >> 3;
    const int pj  = blk * 8 + pjj;
    float creg = c_ws[blk * 256 + tid];

    // prologue: wait for Gx rows of t=0 (mt 0), then load gx[0]
    while (__hip_atomic_load(gcnt, __ATOMIC_RELAXED,
                             __HIP_MEMORY_SCOPE_AGENT) < 64)
        __builtin_amdgcn_s_sleep(1);
    asm volatile("" ::: "memory");
    __builtin_amdgcn_sched_barrier(0);

    unsigned short gxr0, gxr1, gxr2, gxr3;
    {
        const __hip_bfloat16* gx = Gx + (size_t)pb * NG + pj;
        gxr0 = *(const unsigned short*)(gx + 0 * HD);
        gxr1 = *(const unsigned short*)(gx + 1 * HD);
        gxr2 = *(const unsigned short*)(gx + 2 * HD);
        gxr3 = *(const unsigned short*)(gx + 3 * HD);
    }
    int mt_ok = 0;

    for (int tt = 0; tt < T; tt++) {
        const int t = tt;
        const __hip_bfloat16* hb;
        size_t rstride;
        if (t == 0) { hb = hzero; rstride = HD; }
        else        { hb = hs + (size_t)(t - 1) * HD; rstride = (size_t)SEQ * HD; }

        // poll ready for next step's Gx rows (register-cached, 1 load / 2 steps)
        unsigned short ngxr0 = 0, ngxr1 = 0, ngxr2 = 0, ngxr3 = 0;
        if (tt + 1 < T) {
            const int mtn = (tt + 1) >> 1;
            if (mtn > mt_ok) {
                while (__hip_atomic_load(gcnt + mtn * 16, __ATOMIC_RELAXED,
                                         __HIP_MEMORY_SCOPE_AGENT) < 64)
                    __builtin_amdgcn_s_sleep(1);
                mt_ok = mtn;
                asm volatile("" ::: "memory");
                __builtin_amdgcn_sched_barrier(0);
            }
            const __hip_bfloat16* gx1 = Gx + ((size_t)(tt + 1) * BATCH + pb) * NG + pj;
            ngxr0 = *(const unsigned short*)(gx1 + 0 * HD);
            ngxr1 = *(const unsigned short*)(gx1 + 1 * HD);
            ngxr2 = *(const unsigned short*)(gx1 + 2 * HD);
            ngxr3 = *(const unsigned short*)(gx1 + 3 * HD);
        }

        // h @ Wh^T : one A-frag stream feeds BOTH col-tile chains
        const __hip_bfloat16* arow =
            hb + (size_t)(wm * 16 + l16) * rstride + wk * 512 + quad * 8;
        floatx4 acc0 = (floatx4)(0.0f), acc1 = (floatx4)(0.0f);
#pragma unroll
        for (int ks = 0; ks < 16; ks++) {
            shortx8 av = *(const shortx8*)(arow + ks * 32);
            acc0 = MFMA16(av, Bfrag[0][ks], acc0);
            acc1 = MFMA16(av, Bfrag[1][ks], acc1);
        }

        // acc -> LDS [wk][col][b], stride 36 floats (16B-aligned)
        {
            const int b0 = wm * 16 + quad * 4;
            *(floatx4*)(accf + wk * 1168 + (l16)      * 36 + b0) = acc0;
            *(floatx4*)(accf + wk * 1168 + (16 + l16) * 36 + b0) = acc1;
        }
        __syncthreads();

        // pointwise for (pb, pjj); c lives in a register across the launch
        {
            const int i0 = (pjj * 4 + 0) * 36 + pb;
            const int i1 = (pjj * 4 + 1) * 36 + pb;
            const int i2 = (pjj * 4 + 2) * 36 + pb;
            const int i3 = (pjj * 4 + 3) * 36 + pb;
            const float fp = accf[i0] + accf[1168 + i0] + bf2f(gxr0);
            const float ip = accf[i1] + accf[1168 + i1] + bf2f(gxr1);
            const float cp = accf[i2] + accf[1168 + i2] + bf2f(gxr2);
            const float op = accf[i3] + accf[1168 + i3] + bf2f(gxr3);
            const float fg = sigmoidf_(fp);
            const float ig = sigmoidf_(ip);
            const float cg = tanhf_(cp);
            const float og = sigmoidf_(op);
            creg = ig * cg + fg * creg;
            const float hnew = og * tanhf_(creg);

            // packed-u32 relaxed agent store (sc1 => coherence-point visible)
            const unsigned my = (unsigned)(unsigned short)bf16s(hnew);
            const unsigned nb = (unsigned)__shfl_xor((int)my, 1);
            if ((tid & 1) == 0) {
                unsigned* dst = (unsigned*)(hs + ((size_t)pb * SEQ + t) * HD + pj);
                const unsigned packed = my | (nb << 16);
                __hip_atomic_store(dst, packed, __ATOMIC_RELAXED,
                                   __HIP_MEMORY_SCOPE_AGENT);
            }
        }

        // device barrier among CONSUMER blocks. The arrive flag is now
        // published EVERY step (incl. the last: FC workers gate on epoch T).
        __syncthreads();   // per-wave s_waitcnt vmcnt(0): sc1 stores at IF
        if (wv == 0 && lane == 0) {
            __hip_atomic_store(bar + blk * 16, (unsigned)(tt + 1),
                               __ATOMIC_RELAXED, __HIP_MEMORY_SCOPE_AGENT);
        }
        if (tt < T - 1) {
            const unsigned epoch = (unsigned)(tt + 1);
            if (wv == 0) {
                // parallel poll: lane L watches slots L and L+64 (sticky)
                unsigned* p0 = bar + lane * 16;
                unsigned* p1 = bar + (64 + lane) * 16;
                bool d0 = false, d1 = false;
                while (true) {
                    if (!d0) d0 = (__hip_atomic_load(p0, __ATOMIC_RELAXED,
                                       __HIP_MEMORY_SCOPE_AGENT) >= epoch);
                    if (!d1) d1 = (__hip_atomic_load(p1, __ATOMIC_RELAXED,
                                       __HIP_MEMORY_SCOPE_AGENT) >= epoch);
                    if (__all(d0 && d1)) break;
                    __builtin_amdgcn_s_sleep(1);
                }
                asm volatile("" ::: "memory");
                __builtin_amdgcn_sched_barrier(0);
            }
            __syncthreads();
        }

        gxr0 = ngxr0; gxr1 = ngxr1; gxr2 = ngxr2; gxr3 = ngxr3;
    }

    c_ws[blk * 256 + tid] = creg;
}

// ---------------------------------------------------------------------------
// Kernel 3 (FALLBACK only): out[r][n] = sum_k hs[r][k]*Wfc[n][k] + bfc[n]
// ---------------------------------------------------------------------------
__global__ __launch_bounds__(256) void gemm_fc(
    const __hip_bfloat16* __restrict__ hs,
    const __hip_bfloat16* __restrict__ Wfcb,
    const float* __restrict__ bfc,
    float* __restrict__ out)
{
    const int wave = (blockIdx.x << 2) + (threadIdx.x >> 6);
    const int mt = wave >> 4;
    const int nt = wave & 15;
    const int lane = threadIdx.x & 63;
    const int quad = lane >> 4;
    const int l16  = lane & 15;
    const int m0 = mt << 6;
    const int n0 = nt << 6;

    floatx4 acc[4][4];
#pragma unroll
    for (int i = 0; i < 4; i++)
#pragma unroll
        for (int j = 0; j < 4; j++) acc[i][j] = (floatx4)(0.0f);

    const __hip_bfloat16* arow[4];
    const __hip_bfloat16* brow[4];
#pragma unroll
    for (int i = 0; i < 4; i++)
        arow[i] = hs + (size_t)(m0 + i * 16 + l16) * HD + quad * 8;
#pragma unroll
    for (int j = 0; j < 4; j++)
        brow[j] = Wfcb + (size_t)(n0 + j * 16 + l16) * HD + quad * 8;

    for (int k0 = 0; k0 < HD; k0 += 32) {
        shortx8 a[4], b[4];
#pragma unroll
        for (int i = 0; i < 4; i++) a[i] = *(const shortx8*)(arow[i] + k0);
#pragma unroll
        for (int j = 0; j < 4; j++) b[j] = *(const shortx8*)(brow[j] + k0);
#pragma unroll
        for (int i = 0; i < 4; i++)
#pragma unroll
            for (int j = 0; j < 4; j++)
                acc[i][j] = MFMA16(a[i], b[j], acc[i][j]);
    }

#pragma unroll
    for (int j = 0; j < 4; j++) {
        const int n = n0 + j * 16 + l16;
        const float bias = bfc[n];
#pragma unroll
        for (int i = 0; i < 4; i++) {
#pragma unroll
            for (int r = 0; r < 4; r++) {
                const int row = m0 + i * 16 + quad * 4 + r;
                out[(size_t)row * 1024 + n] = acc[i][j][r] + bias;
            }
        }
    }
}

// ---------------------------------------------------------------------------
extern "C" void kernel_launch(void* const* d_in, const int* in_sizes, int n_in,
                              void* d_out, int out_size, void* d_ws, size_t ws_size,
                              hipStream_t stream) {
    const float* x   = (const float*)d_in[0];
    const float* Wf  = (const float*)d_in[1];
    const float* bf_ = (const float*)d_in[2];
    const float* Wi  = (const float*)d_in[3];
    const float* bi_ = (const float*)d_in[4];
    const float* Wc  = (const float*)d_in[5];
    const float* bc_ = (const float*)d_in[6];
    const float* Wo  = (const float*)d_in[7];
    const float* bo_ = (const float*)d_in[8];
    const float* Wfc = (const float*)d_in[9];
    const float* bfc = (const float*)d_in[10];
    float* out = (float*)d_out;

    // ---- ws layout (bytes) ----
    char* ws = (char*)d_ws;
    const size_t WB_OFF  = 0;                                          // 16 MiB
    const size_t WFC_OFF = (size_t)4 * WG_ELEMS * 2;                   // +2 MiB
    const size_t HS_OFF  = WFC_OFF + (size_t)HD * HD * 2;              // +32 MiB
    const size_t ST_OFF  = HS_OFF + (size_t)BATCH * SEQ * HD * 2;
    const size_t HZ_BYTES  = (size_t)BATCH * HD * 2;                   // 64 KiB
    const size_t C_BYTES   = (size_t)PBLK * 256 * 4;                   // 128 KiB
    const size_t BAR_BYTES = 128 * 64 + 256 * 64;  // arrive slots + gcnt[256]
    const size_t ST_BYTES  = HZ_BYTES + C_BYTES + BAR_BYTES;
    const size_t GX_OFF  = ST_OFF + ST_BYTES;

    __hip_bfloat16* Wb    = (__hip_bfloat16*)(ws + WB_OFF);
    __hip_bfloat16* Wfcb  = (__hip_bfloat16*)(ws + WFC_OFF);
    __hip_bfloat16* hs    = (__hip_bfloat16*)(ws + HS_OFF);
    __hip_bfloat16* hzero = (__hip_bfloat16*)(ws + ST_OFF);
    float*          cbuf  = (float*)(ws + ST_OFF + HZ_BYTES);
    unsigned*       bar   = (unsigned*)(ws + ST_OFF + HZ_BYTES + C_BYTES);
    __hip_bfloat16* Gx    = (__hip_bfloat16*)(ws + GX_OFF);

    // fast path needs the full Gx array (128 MiB)
    const size_t GX_FULL = (size_t)SEQ * BATCH * NG * 2;
    const int persist = (GX_OFF + GX_FULL <= ws_size);
    int T_CHUNK = 1;
    if (!persist) {
        const size_t GX_STEP = (size_t)BATCH * NG * 2;   // 256 KiB per step
        const int fopts[3] = {8, 2, 1};
        for (int i = 0; i < 3; i++) {
            if (GX_OFF + (size_t)fopts[i] * GX_STEP <= ws_size) {
                T_CHUNK = fopts[i]; break;
            }
        }
    }

    // one-time weight conversion fp32 -> bf16
    cvt_f32_bf16<<<2048, 256, 0, stream>>>(Wf, Wb + 0 * (size_t)WG_ELEMS, WG_ELEMS);
    cvt_f32_bf16<<<2048, 256, 0, stream>>>(Wi, Wb + 1 * (size_t)WG_ELEMS, WG_ELEMS);
    cvt_f32_bf16<<<2048, 256, 0, stream>>>(Wc, Wb + 2 * (size_t)WG_ELEMS, WG_ELEMS);
    cvt_f32_bf16<<<2048, 256, 0, stream>>>(Wo, Wb + 3 * (size_t)WG_ELEMS, WG_ELEMS);
    cvt_f32_bf16<<<1024, 256, 0, stream>>>(Wfc, Wfcb, HD * HD);

    // zero hzero, c, barrier + ready-counter state (ws poisoned every launch)
    hipMemsetAsync(ws + ST_OFF, 0, ST_BYTES, stream);

    if (persist) {
        // single launch: 128 consumer + 128 producer/FC blocks (256 CUs)
        lstm_persist<<<2 * PBLK, 256, 0, stream>>>(
            Wb, x, Gx, bf_, bi_, bc_, bo_, Wfcb, bfc, out,
            SEQ, hzero, cbuf, hs, bar);
    } else {
        for (int t0 = 0; t0 < SEQ; t0 += T_CHUNK) {
            gemm_gx<<<T_CHUNK * 8, 256, 0, stream>>>(
                x, Wb, bf_, bi_, bc_, bo_, Gx, t0);
            for (int t = t0; t < t0 + T_CHUNK; t++) {
                const __hip_bfloat16* gx_t = Gx + (size_t)(t - t0) * BATCH * NG;
                lstm_step<<<16, 256, 0, stream>>>(gx_t, t, Wb, hzero, cbuf, hs);
            }
        }
        gemm_fc<<<1024, 256, 0, stream>>>(hs, Wfcb, bfc, out);
    }
}

// Round 9
// 2387.632 us; speedup vs baseline: 1.4817x; 1.1535x over previous
//
#include <hip/hip_runtime.h>
#include <hip/hip_bf16.h>

#define BATCH 32
#define SEQ   512
#define IND   1024
#define HD    1024
#define ZD    2048   // IN + H
#define NG    4096   // 4*H
#define WG_ELEMS (1024 * 2048)   // elements per gate weight matrix
#define PBLK 128                 // consumer grid size (producers: PBLK..2*PBLK)
#define FSTR 68                  // flag slot stride in u32 (272B: stripes channels)

typedef short  shortx8 __attribute__((ext_vector_type(8)));
typedef float  floatx4 __attribute__((ext_vector_type(4)));

#define MFMA16(a, b, c) __builtin_amdgcn_mfma_f32_16x16x32_bf16((a), (b), (c), 0, 0, 0)

__device__ __forceinline__ float sigmoidf_(float x) {
    return 1.0f / (1.0f + __expf(-x));
}
__device__ __forceinline__ float tanhf_(float x) {
    return 1.0f - 2.0f / (__expf(2.0f * x) + 1.0f);
}

__device__ __forceinline__ short bf16s(float x) {
    __hip_bfloat16 h = __float2bfloat16(x);
    return *reinterpret_cast<short*>(&h);
}

__device__ __forceinline__ float bf2f(unsigned short u) {
    unsigned v = ((unsigned)u) << 16;
    float f;
    __builtin_memcpy(&f, &v, 4);
    return f;
}

__device__ __forceinline__ shortx8 cvt8(const float* __restrict__ p) {
    float4 v0 = *(const float4*)p;
    float4 v1 = *(const float4*)(p + 4);
    shortx8 r;
    r[0] = bf16s(v0.x); r[1] = bf16s(v0.y); r[2] = bf16s(v0.z); r[3] = bf16s(v0.w);
    r[4] = bf16s(v1.x); r[5] = bf16s(v1.y); r[6] = bf16s(v1.z); r[7] = bf16s(v1.w);
    return r;
}

// ---------------------------------------------------------------------------
// Fused fp32 -> bf16 conversion of ALL weights in one launch (v11: replaces
// five serial cvt launches, ~30-40us of prologue).
// grid = 4*2048 (gates) + 1024 (Wfc) = 9216 blocks x 256.
// ---------------------------------------------------------------------------
__global__ __launch_bounds__(256) void cvt_weights(
    const float* __restrict__ Wf, const float* __restrict__ Wi,
    const float* __restrict__ Wc, const float* __restrict__ Wo,
    const float* __restrict__ Wfc,
    __hip_bfloat16* __restrict__ Wb, __hip_bfloat16* __restrict__ Wfcb)
{
    int b = blockIdx.x;
    const float* src;
    __hip_bfloat16* dst;
    if (b < 8192) {
        const int g = b >> 11;
        src = (g == 0) ? Wf : (g == 1) ? Wi : (g == 2) ? Wc : Wo;
        dst = Wb + (size_t)g * WG_ELEMS;
        b &= 2047;
    } else {
        src = Wfc; dst = Wfcb; b -= 8192;
    }
    const int i = (b * 256 + threadIdx.x) * 4;
    float4 v = *(const float4*)(src + i);
    dst[i + 0] = __float2bfloat16(v.x);
    dst[i + 1] = __float2bfloat16(v.y);
    dst[i + 2] = __float2bfloat16(v.z);
    dst[i + 3] = __float2bfloat16(v.w);
}

// ---------------------------------------------------------------------------
// Kernel 1 (FALLBACK only): x-part gate pre-activations for a chunk of T
// steps. Gx[(t-t0)*B + b][g*1024+j] = sum_k x[b][t][k]*Wg[j][1024+k] + bias.
// grid = T*8 blocks of 256.
// ---------------------------------------------------------------------------
__global__ __launch_bounds__(256) void gemm_gx(
    const float* __restrict__ x,
    const __hip_bfloat16* __restrict__ Wb,     // [4][1024][2048] bf16
    const float* __restrict__ bf_, const float* __restrict__ bi_,
    const float* __restrict__ bc_, const float* __restrict__ bo_,
    __hip_bfloat16* __restrict__ Gx, const int t0)
{
    const int wave = (blockIdx.x << 2) + (threadIdx.x >> 6);
    const int mt = wave >> 6;
    const int nt = wave & 63;
    const int lane = threadIdx.x & 63;
    const int quad = lane >> 4;
    const int l16  = lane & 15;
    const int m0 = mt << 6;
    const int n0 = nt << 6;
    const int g  = n0 >> 10;
    const __hip_bfloat16* Wg = Wb + (size_t)g * WG_ELEMS;
    const float* bg = (g == 0) ? bf_ : (g == 1) ? bi_ : (g == 2) ? bc_ : bo_;
    const int j0 = n0 & 1023;

    floatx4 acc[4][4];
#pragma unroll
    for (int i = 0; i < 4; i++)
#pragma unroll
        for (int j = 0; j < 4; j++) acc[i][j] = (floatx4)(0.0f);

    const float* arow[4];
    const __hip_bfloat16* brow[4];
#pragma unroll
    for (int i = 0; i < 4; i++) {
        const int r = m0 + i * 16 + l16;
        const int t = t0 + (r >> 5);
        const int b = r & 31;
        arow[i] = x + ((size_t)b * SEQ + t) * IND + quad * 8;
    }
#pragma unroll
    for (int j = 0; j < 4; j++)
        brow[j] = Wg + (size_t)(j0 + j * 16 + l16) * ZD + HD + quad * 8;

    for (int k0 = 0; k0 < IND; k0 += 32) {
        shortx8 a[4], b[4];
#pragma unroll
        for (int i = 0; i < 4; i++) a[i] = cvt8(arow[i] + k0);
#pragma unroll
        for (int j = 0; j < 4; j++) b[j] = *(const shortx8*)(brow[j] + k0);
#pragma unroll
        for (int i = 0; i < 4; i++)
#pragma unroll
            for (int j = 0; j < 4; j++)
                acc[i][j] = MFMA16(a[i], b[j], acc[i][j]);
    }

#pragma unroll
    for (int j = 0; j < 4; j++) {
        const int n  = n0 + j * 16 + l16;
        const int jj = j0 + j * 16 + l16;
        const float bias = bg[jj];
#pragma unroll
        for (int i = 0; i < 4; i++) {
#pragma unroll
            for (int r = 0; r < 4; r++) {
                const int row = m0 + i * 16 + quad * 4 + r;
                Gx[(size_t)row * NG + n] = __float2bfloat16(acc[i][j][r] + bias);
            }
        }
    }
}

// ---------------------------------------------------------------------------
// Kernel 2 (FALLBACK, small-ws path): one LSTM time step, hs-direct h I/O.
// ---------------------------------------------------------------------------
__global__ __launch_bounds__(256) void lstm_step(
    const __hip_bfloat16* __restrict__ gx,
    const int t,
    const __hip_bfloat16* __restrict__ Wb,
    const __hip_bfloat16* __restrict__ hzero,  // [B][H] zeros
    float* __restrict__ c,
    __hip_bfloat16* __restrict__ hs)           // [B][S][H]
{
    const int jt = (blockIdx.x << 2) + (threadIdx.x >> 6);
    const int lane = threadIdx.x & 63;
    const int quad = lane >> 4;
    const int l16  = lane & 15;
    const int j0   = jt << 4;

    const __hip_bfloat16* hb;
    size_t rstride;
    if (t == 0) { hb = hzero; rstride = HD; }
    else        { hb = hs + (size_t)(t - 1) * HD; rstride = (size_t)SEQ * HD; }

    const __hip_bfloat16* wrow[4];
#pragma unroll
    for (int g = 0; g < 4; g++)
        wrow[g] = Wb + (size_t)g * WG_ELEMS + (size_t)(j0 + l16) * ZD + quad * 8;

    const __hip_bfloat16* hrow0 = hb + (size_t)l16 * rstride + quad * 8;
    const __hip_bfloat16* hrow1 = hb + (size_t)(16 + l16) * rstride + quad * 8;

    floatx4 acc[4][2];
#pragma unroll
    for (int g = 0; g < 4; g++) { acc[g][0] = (floatx4)(0.0f); acc[g][1] = (floatx4)(0.0f); }

    for (int k0 = 0; k0 < HD; k0 += 32) {
        shortx8 a0 = *(const shortx8*)(hrow0 + k0);
        shortx8 a1 = *(const shortx8*)(hrow1 + k0);
#pragma unroll
        for (int g = 0; g < 4; g++) {
            shortx8 bfrag = *(const shortx8*)(wrow[g] + k0);
            acc[g][0] = MFMA16(a0, bfrag, acc[g][0]);
            acc[g][1] = MFMA16(a1, bfrag, acc[g][1]);
        }
    }

    const int j = j0 + l16;
#pragma unroll
    for (int i = 0; i < 2; i++) {
#pragma unroll
        for (int r = 0; r < 4; r++) {
            const int bb = i * 16 + quad * 4 + r;
            const size_t gbase = (size_t)bb * NG + j;
            const float fp = acc[0][i][r] + __bfloat162float(gx[gbase + 0 * HD]);
            const float ip = acc[1][i][r] + __bfloat162float(gx[gbase + 1 * HD]);
            const float cp = acc[2][i][r] + __bfloat162float(gx[gbase + 2 * HD]);
            const float op = acc[3][i][r] + __bfloat162float(gx[gbase + 3 * HD]);
            const float fg = sigmoidf_(fp);
            const float ig = sigmoidf_(ip);
            const float cg = tanhf_(cp);
            const float og = sigmoidf_(op);
            const size_t ci = (size_t)bb * HD + j;
            const float cnew = ig * cg + fg * c[ci];
            const float hnew = og * tanhf_(cnew);
            c[ci] = cnew;
            hs[((size_t)bb * SEQ + t) * HD + j] = __float2bfloat16(hnew);
        }
    }
}

// ---------------------------------------------------------------------------
// Kernel 2' (FAST path): persistent recurrence + concurrent Gx + fused FC, v11.
//
// v11 sync changes (protocol logic otherwise = v10):
//  - PER-WAVE HALF-BARRIER: consumer wave wk reads h columns [wk*512,+512),
//    i.e. j-cols of source blocks [wk*64, wk*64+64) ONLY. Each wave polls
//    just those 64 flags (one slot per lane, divergent-while sticky exit),
//    instead of wave0 polling all 128 + a broadcast __syncthreads. Halves
//    the straggler set per wave, removes one barrier, lets wk-halves overlap.
//  - FC gate poll is wave0-only + __syncthreads broadcast (was all 4 waves:
//    4x the sc1 poll traffic on the same flag lines consumers poll).
//  - Flag/counter slots at 272B stride (odd multiple of 16 -> stripes across
//    memory channels for any pow-2 interleave; polls are uncached sc1 loads
//    hitting the slots' home L2/IF every iteration).
// Memory ordering unchanged from v5/v10: data stores are relaxed sc1 (land at
// IF), each wave's vmcnt(0) drain happens at the pre-s_barrier of the second
// __syncthreads, flag store issues after that barrier completes.
// ---------------------------------------------------------------------------
__global__ __launch_bounds__(256, 1) void lstm_persist(
    const __hip_bfloat16* __restrict__ Wb,     // [4][1024][2048] bf16
    const float* __restrict__ x,               // [B][S][IND] fp32
    __hip_bfloat16* __restrict__ Gx,           // [S*B][NG] bf16 (full)
    const float* __restrict__ bf_, const float* __restrict__ bi_,
    const float* __restrict__ bc_, const float* __restrict__ bo_,
    const __hip_bfloat16* __restrict__ Wfcb,   // [1024][1024] bf16
    const float* __restrict__ bfc,
    float* __restrict__ out,                   // [B*S][1024] fp32
    const int T,
    const __hip_bfloat16* __restrict__ hzero,  // [B][H] zeros
    float* __restrict__ c_ws,                  // [PBLK*256] fp32
    __hip_bfloat16* __restrict__ hs,           // [B][S][H] bf16
    unsigned* __restrict__ bar)  // arrive[128]*FSTR; +128*FSTR: gcnt[256]*FSTR
{
    __shared__ float accf[2 * 1168];

    const int tid  = threadIdx.x;
    const int blk  = blockIdx.x;
    const int wv   = tid >> 6;
    const int lane = tid & 63;
    const int quad = lane >> 4;
    const int l16  = lane & 15;
    unsigned* gcnt = bar + 128 * FSTR;

    if (blk >= PBLK) {
        // ========================= PRODUCER =========================
        const int pb_ = blk - PBLK;              // 0..127
        const int pw = pb_ * 4 + wv;             // 0..511
        {
            const int nt = pw & 63;              // fixed col-tile (W stays L2-hot)
            const int n0 = nt << 6;
            const int g  = n0 >> 10;
            const __hip_bfloat16* Wg = Wb + (size_t)g * WG_ELEMS;
            const float* bg = (g == 0) ? bf_ : (g == 1) ? bi_ : (g == 2) ? bc_ : bo_;
            const int j0 = n0 & 1023;

            const __hip_bfloat16* brow[4];
#pragma unroll
            for (int j = 0; j < 4; j++)
                brow[j] = Wg + (size_t)(j0 + j * 16 + l16) * ZD + HD + quad * 8;

            float bias[4];
#pragma unroll
            for (int j = 0; j < 4; j++) bias[j] = bg[j0 + j * 16 + l16];

            for (int it = 0; it < 32; it++) {
                const int mt = (pw >> 6) + 8 * it;  // rows [mt*64, +64) = t-pair
                const int m0 = mt << 6;

                floatx4 acc[4][4];
#pragma unroll
                for (int i = 0; i < 4; i++)
#pragma unroll
                    for (int j = 0; j < 4; j++) acc[i][j] = (floatx4)(0.0f);

                const float* arow[4];
#pragma unroll
                for (int i = 0; i < 4; i++) {
                    const int r = m0 + i * 16 + l16;
                    const int t = r >> 5;
                    const int b = r & 31;
                    arow[i] = x + ((size_t)b * SEQ + t) * IND + quad * 8;
                }

                for (int k0 = 0; k0 < IND; k0 += 32) {
                    shortx8 a[4], b[4];
#pragma unroll
                    for (int i = 0; i < 4; i++) a[i] = cvt8(arow[i] + k0);
#pragma unroll
                    for (int j = 0; j < 4; j++) b[j] = *(const shortx8*)(brow[j] + k0);
#pragma unroll
                    for (int i = 0; i < 4; i++)
#pragma unroll
                        for (int j = 0; j < 4; j++)
                            acc[i][j] = MFMA16(a[i], b[j], acc[i][j]);
                }

                // packed-u32 relaxed sc1 stores (coherence-point visible)
#pragma unroll
                for (int j = 0; j < 4; j++) {
                    const int n = n0 + j * 16 + l16;
#pragma unroll
                    for (int i = 0; i < 4; i++) {
#pragma unroll
                        for (int r = 0; r < 4; r++) {
                            const int row = m0 + i * 16 + quad * 4 + r;
                            const float v = acc[i][j][r] + bias[j];
                            const unsigned my = (unsigned)(unsigned short)bf16s(v);
                            const unsigned nb = (unsigned)__shfl_xor((int)my, 1);
                            if ((l16 & 1) == 0) {
                                unsigned* dst = (unsigned*)(Gx + (size_t)row * NG + n);
                                __hip_atomic_store(dst, my | (nb << 16),
                                                   __ATOMIC_RELAXED,
                                                   __HIP_MEMORY_SCOPE_AGENT);
                            }
                        }
                    }
                }
                // drain sc1 data stores to the coherence point, then signal
                asm volatile("s_waitcnt vmcnt(0)" ::: "memory");
                if (lane == 0)
                    __hip_atomic_fetch_add(gcnt + (size_t)mt * FSTR, 1u,
                                           __ATOMIC_RELAXED, __HIP_MEMORY_SCOPE_AGENT);
            }
        }

        // ---------------- FC phase: out = hs @ Wfc^T + bfc ----------------
        {
            const int fb  = (pb_ & 7) * 4 + wv;  // batch 0..31 (same-XCD group)
            const int fnt = pb_ >> 3;            // col-tile 0..15
            const int n0  = fnt << 6;

            const __hip_bfloat16* brow[4];
#pragma unroll
            for (int j = 0; j < 4; j++)
                brow[j] = Wfcb + (size_t)(n0 + j * 16 + l16) * HD + quad * 8;
            float biasf[4];
#pragma unroll
            for (int j = 0; j < 4; j++) biasf[j] = bfc[n0 + j * 16 + l16];

            for (int tc = 0; tc < 8; tc++) {
                // gate: all consumer epochs >= (tc+1)*64 — wave0 polls, then
                // __syncthreads broadcasts (v11: was all 4 waves polling)
                const unsigned need = (unsigned)((tc + 1) * 64);
                if (wv == 0) {
                    unsigned* p0 = bar + (size_t)lane * FSTR;
                    unsigned* p1 = bar + (size_t)(64 + lane) * FSTR;
                    bool d0 = false, d1 = false;
                    while (true) {
                        if (!d0) d0 = (__hip_atomic_load(p0, __ATOMIC_RELAXED,
                                           __HIP_MEMORY_SCOPE_AGENT) >= need);
                        if (!d1) d1 = (__hip_atomic_load(p1, __ATOMIC_RELAXED,
                                           __HIP_MEMORY_SCOPE_AGENT) >= need);
                        if (__all(d0 && d1)) break;
                        __builtin_amdgcn_s_sleep(8);
                    }
                    asm volatile("" ::: "memory");
                    __builtin_amdgcn_sched_barrier(0);
                }
                __syncthreads();

                const int m0 = fb * SEQ + tc * 64;

                floatx4 acc[4][4];
#pragma unroll
                for (int i = 0; i < 4; i++)
#pragma unroll
                    for (int j = 0; j < 4; j++) acc[i][j] = (floatx4)(0.0f);

                const __hip_bfloat16* arow[4];
#pragma unroll
                for (int i = 0; i < 4; i++)
                    arow[i] = hs + (size_t)(m0 + i * 16 + l16) * HD + quad * 8;

                for (int k0 = 0; k0 < HD; k0 += 32) {
                    shortx8 a[4], b[4];
#pragma unroll
                    for (int i = 0; i < 4; i++) a[i] = *(const shortx8*)(arow[i] + k0);
#pragma unroll
                    for (int j = 0; j < 4; j++) b[j] = *(const shortx8*)(brow[j] + k0);
#pragma unroll
                    for (int i = 0; i < 4; i++)
#pragma unroll
                        for (int j = 0; j < 4; j++)
                            acc[i][j] = MFMA16(a[i], b[j], acc[i][j]);
                }

#pragma unroll
                for (int j = 0; j < 4; j++) {
                    const int n = n0 + j * 16 + l16;
#pragma unroll
                    for (int i = 0; i < 4; i++) {
#pragma unroll
                        for (int r = 0; r < 4; r++) {
                            const int row = m0 + i * 16 + quad * 4 + r;
                            out[(size_t)row * 1024 + n] = acc[i][j][r] + biasf[j];
                        }
                    }
                }
            }
        }
        return;
    }

    // ========================= CONSUMER =========================
    const int wm = wv & 1;           // batch-half tile
    const int wk = wv >> 1;          // K-half

    shortx8 Bfrag[2][16];
#pragma unroll
    for (int ct = 0; ct < 2; ct++) {
        const int lc = ct * 16 + l16;
        const int jj = lc >> 2, g = lc & 3;
        const __hip_bfloat16* wr =
            Wb + (size_t)g * WG_ELEMS + (size_t)(blk * 8 + jj) * ZD + wk * 512 + quad * 8;
#pragma unroll
        for (int ks = 0; ks < 16; ks++)
            Bfrag[ct][ks] = *(const shortx8*)(wr + ks * 32);
    }

    const int pjj = tid & 7;
    const int pb  = tid >> 3;
    const int pj  = blk * 8 + pjj;
    float creg = c_ws[blk * 256 + tid];

    // prologue: wait for Gx rows of t=0 (mt 0) — wave0 polls, sync broadcasts
    if (wv == 0) {
        while (__hip_atomic_load(gcnt, __ATOMIC_RELAXED,
                                 __HIP_MEMORY_SCOPE_AGENT) < 64)
            __builtin_amdgcn_s_sleep(1);
        asm volatile("" ::: "memory");
        __builtin_amdgcn_sched_barrier(0);
    }
    __syncthreads();

    unsigned short gxr0, gxr1, gxr2, gxr3;
    {
        const __hip_bfloat16* gx = Gx + (size_t)pb * NG + pj;
        gxr0 = *(const unsigned short*)(gx + 0 * HD);
        gxr1 = *(const unsigned short*)(gx + 1 * HD);
        gxr2 = *(const unsigned short*)(gx + 2 * HD);
        gxr3 = *(const unsigned short*)(gx + 3 * HD);
    }
    int mt_ok = 0;

    // this wave's flag slot to watch: source blocks [wk*64, wk*64+64)
    unsigned* mywatch = bar + (size_t)(wk * 64 + lane) * FSTR;

    for (int tt = 0; tt < T; tt++) {
        const int t = tt;
        const __hip_bfloat16* hb;
        size_t rstride;
        if (t == 0) { hb = hzero; rstride = HD; }
        else        { hb = hs + (size_t)(t - 1) * HD; rstride = (size_t)SEQ * HD; }

        // gx prefetch for tt+1 (gcnt-gated; issues before the flag poll so
        // the loads complete under the spin)
        unsigned short ngxr0 = 0, ngxr1 = 0, ngxr2 = 0, ngxr3 = 0;
        if (tt + 1 < T) {
            const int mtn = (tt + 1) >> 1;
            if (mtn > mt_ok) {
                while (__hip_atomic_load(gcnt + (size_t)mtn * FSTR, __ATOMIC_RELAXED,
                                         __HIP_MEMORY_SCOPE_AGENT) < 64)
                    __builtin_amdgcn_s_sleep(1);
                mt_ok = mtn;
                asm volatile("" ::: "memory");
                __builtin_amdgcn_sched_barrier(0);
            }
            const __hip_bfloat16* gx1 = Gx + ((size_t)(tt + 1) * BATCH + pb) * NG + pj;
            ngxr0 = *(const unsigned short*)(gx1 + 0 * HD);
            ngxr1 = *(const unsigned short*)(gx1 + 1 * HD);
            ngxr2 = *(const unsigned short*)(gx1 + 2 * HD);
            ngxr3 = *(const unsigned short*)(gx1 + 3 * HD);
        }

        // v11 per-wave half-barrier: wait for this wave's 64 source blocks
        // to have published epoch >= tt (h[tt-1] drained to IF). Divergent
        // while = sticky per-lane exit; wave proceeds when all lanes pass.
        if (tt > 0) {
            while (__hip_atomic_load(mywatch, __ATOMIC_RELAXED,
                                     __HIP_MEMORY_SCOPE_AGENT) < (unsigned)tt)
                __builtin_amdgcn_s_sleep(1);
            asm volatile("" ::: "memory");
            __builtin_amdgcn_sched_barrier(0);
        }

        // h @ Wh^T : one A-frag stream feeds BOTH col-tile chains
        const __hip_bfloat16* arow =
            hb + (size_t)(wm * 16 + l16) * rstride + wk * 512 + quad * 8;
        floatx4 acc0 = (floatx4)(0.0f), acc1 = (floatx4)(0.0f);
#pragma unroll
        for (int ks = 0; ks < 16; ks++) {
            shortx8 av = *(const shortx8*)(arow + ks * 32);
            acc0 = MFMA16(av, Bfrag[0][ks], acc0);
            acc1 = MFMA16(av, Bfrag[1][ks], acc1);
        }

        // acc -> LDS [wk][col][b], stride 36 floats (16B-aligned)
        {
            const int b0 = wm * 16 + quad * 4;
            *(floatx4*)(accf + wk * 1168 + (l16)      * 36 + b0) = acc0;
            *(floatx4*)(accf + wk * 1168 + (16 + l16) * 36 + b0) = acc1;
        }
        __syncthreads();   // (A) panels complete

        // pointwise for (pb, pjj); c lives in a register across the launch
        {
            const int i0 = (pjj * 4 + 0) * 36 + pb;
            const int i1 = (pjj * 4 + 1) * 36 + pb;
            const int i2 = (pjj * 4 + 2) * 36 + pb;
            const int i3 = (pjj * 4 + 3) * 36 + pb;
            const float fp = accf[i0] + accf[1168 + i0] + bf2f(gxr0);
            const float ip = accf[i1] + accf[1168 + i1] + bf2f(gxr1);
            const float cp = accf[i2] + accf[1168 + i2] + bf2f(gxr2);
            const float op = accf[i3] + accf[1168 + i3] + bf2f(gxr3);
            const float fg = sigmoidf_(fp);
            const float ig = sigmoidf_(ip);
            const float cg = tanhf_(cp);
            const float og = sigmoidf_(op);
            creg = ig * cg + fg * creg;
            const float hnew = og * tanhf_(creg);

            // packed-u32 relaxed agent store (sc1 => coherence-point visible)
            const unsigned my = (unsigned)(unsigned short)bf16s(hnew);
            const unsigned nb = (unsigned)__shfl_xor((int)my, 1);
            if ((tid & 1) == 0) {
                unsigned* dst = (unsigned*)(hs + ((size_t)pb * SEQ + t) * HD + pj);
                const unsigned packed = my | (nb << 16);
                __hip_atomic_store(dst, packed, __ATOMIC_RELAXED,
                                   __HIP_MEMORY_SCOPE_AGENT);
            }
        }

        __syncthreads();   // (B) accf reads done; each wave's vmcnt(0) drains
                           //     its sc1 h stores to the coherence point
        // publish arrival AFTER the drain barrier (ordering argument = v5);
        // published every step incl. the last (FC workers gate on epoch T)
        if (wv == 0 && lane == 0) {
            __hip_atomic_store(bar + (size_t)blk * FSTR, (unsigned)(tt + 1),
                               __ATOMIC_RELAXED, __HIP_MEMORY_SCOPE_AGENT);
        }

        gxr0 = ngxr0; gxr1 = ngxr1; gxr2 = ngxr2; gxr3 = ngxr3;
    }

    c_ws[blk * 256 + tid] = creg;
}

// ---------------------------------------------------------------------------
// Kernel 3 (FALLBACK only): out[r][n] = sum_k hs[r][k]*Wfc[n][k] + bfc[n]
// ---------------------------------------------------------------------------
__global__ __launch_bounds__(256) void gemm_fc(
    const __hip_bfloat16* __restrict__ hs,
    const __hip_bfloat16* __restrict__ Wfcb,
    const float* __restrict__ bfc,
    float* __restrict__ out)
{
    const int wave = (blockIdx.x << 2) + (threadIdx.x >> 6);
    const int mt = wave >> 4;
    const int nt = wave & 15;
    const int lane = threadIdx.x & 63;
    const int quad = lane >> 4;
    const int l16  = lane & 15;
    const int m0 = mt << 6;
    const int n0 = nt << 6;

    floatx4 acc[4][4];
#pragma unroll
    for (int i = 0; i < 4; i++)
#pragma unroll
        for (int j = 0; j < 4; j++) acc[i][j] = (floatx4)(0.0f);

    const __hip_bfloat16* arow[4];
    const __hip_bfloat16* brow[4];
#pragma unroll
    for (int i = 0; i < 4; i++)
        arow[i] = hs + (size_t)(m0 + i * 16 + l16) * HD + quad * 8;
#pragma unroll
    for (int j = 0; j < 4; j++)
        brow[j] = Wfcb + (size_t)(n0 + j * 16 + l16) * HD + quad * 8;

    for (int k0 = 0; k0 < HD; k0 += 32) {
        shortx8 a[4], b[4];
#pragma unroll
        for (int i = 0; i < 4; i++) a[i] = *(const shortx8*)(arow[i] + k0);
#pragma unroll
        for (int j = 0; j < 4; j++) b[j] = *(const shortx8*)(brow[j] + k0);
#pragma unroll
        for (int i = 0; i < 4; i++)
#pragma unroll
            for (int j = 0; j < 4; j++)
                acc[i][j] = MFMA16(a[i], b[j], acc[i][j]);
    }

#pragma unroll
    for (int j = 0; j < 4; j++) {
        const int n = n0 + j * 16 + l16;
        const float bias = bfc[n];
#pragma unroll
        for (int i = 0; i < 4; i++) {
#pragma unroll
            for (int r = 0; r < 4; r++) {
                const int row = m0 + i * 16 + quad * 4 + r;
                out[(size_t)row * 1024 + n] = acc[i][j][r] + bias;
            }
        }
    }
}

// ---------------------------------------------------------------------------
extern "C" void kernel_launch(void* const* d_in, const int* in_sizes, int n_in,
                              void* d_out, int out_size, void* d_ws, size_t ws_size,
                              hipStream_t stream) {
    const float* x   = (const float*)d_in[0];
    const float* Wf  = (const float*)d_in[1];
    const float* bf_ = (const float*)d_in[2];
    const float* Wi  = (const float*)d_in[3];
    const float* bi_ = (const float*)d_in[4];
    const float* Wc  = (const float*)d_in[5];
    const float* bc_ = (const float*)d_in[6];
    const float* Wo  = (const float*)d_in[7];
    const float* bo_ = (const float*)d_in[8];
    const float* Wfc = (const float*)d_in[9];
    const float* bfc = (const float*)d_in[10];
    float* out = (float*)d_out;

    // ---- ws layout (bytes) ----
    char* ws = (char*)d_ws;
    const size_t WB_OFF  = 0;                                          // 16 MiB
    const size_t WFC_OFF = (size_t)4 * WG_ELEMS * 2;                   // +2 MiB
    const size_t HS_OFF  = WFC_OFF + (size_t)HD * HD * 2;              // +32 MiB
    const size_t ST_OFF  = HS_OFF + (size_t)BATCH * SEQ * HD * 2;
    const size_t HZ_BYTES  = (size_t)BATCH * HD * 2;                   // 64 KiB
    const size_t C_BYTES   = (size_t)PBLK * 256 * 4;                   // 128 KiB
    const size_t BAR_BYTES = (size_t)(128 + 256) * FSTR * 4;           // ~102 KiB
    const size_t ST_BYTES  = HZ_BYTES + C_BYTES + BAR_BYTES;
    const size_t GX_OFF  = ST_OFF + ST_BYTES;

    __hip_bfloat16* Wb    = (__hip_bfloat16*)(ws + WB_OFF);
    __hip_bfloat16* Wfcb  = (__hip_bfloat16*)(ws + WFC_OFF);
    __hip_bfloat16* hs    = (__hip_bfloat16*)(ws + HS_OFF);
    __hip_bfloat16* hzero = (__hip_bfloat16*)(ws + ST_OFF);
    float*          cbuf  = (float*)(ws + ST_OFF + HZ_BYTES);
    unsigned*       bar   = (unsigned*)(ws + ST_OFF + HZ_BYTES + C_BYTES);
    __hip_bfloat16* Gx    = (__hip_bfloat16*)(ws + GX_OFF);

    // fast path needs the full Gx array (128 MiB)
    const size_t GX_FULL = (size_t)SEQ * BATCH * NG * 2;
    const int persist = (GX_OFF + GX_FULL <= ws_size);
    int T_CHUNK = 1;
    if (!persist) {
        const size_t GX_STEP = (size_t)BATCH * NG * 2;   // 256 KiB per step
        const int fopts[3] = {8, 2, 1};
        for (int i = 0; i < 3; i++) {
            if (GX_OFF + (size_t)fopts[i] * GX_STEP <= ws_size) {
                T_CHUNK = fopts[i]; break;
            }
        }
    }

    // one-time weight conversion fp32 -> bf16 (single fused launch, v11)
    cvt_weights<<<9216, 256, 0, stream>>>(Wf, Wi, Wc, Wo, Wfc, Wb, Wfcb);

    // zero hzero, c, barrier + ready-counter state (ws poisoned every launch)
    hipMemsetAsync(ws + ST_OFF, 0, ST_BYTES, stream);

    if (persist) {
        // single launch: 128 consumer + 128 producer/FC blocks (256 CUs)
        lstm_persist<<<2 * PBLK, 256, 0, stream>>>(
            Wb, x, Gx, bf_, bi_, bc_, bo_, Wfcb, bfc, out,
            SEQ, hzero, cbuf, hs, bar);
    } else {
        for (int t0 = 0; t0 < SEQ; t0 += T_CHUNK) {
            gemm_gx<<<T_CHUNK * 8, 256, 0, stream>>>(
                x, Wb, bf_, bi_, bc_, bo_, Gx, t0);
            for (int t = t0; t < t0 + T_CHUNK; t++) {
                const __hip_bfloat16* gx_t = Gx + (size_t)(t - t0) * BATCH * NG;
                lstm_step<<<16, 256, 0, stream>>>(gx_t, t, Wb, hzero, cbuf, hs);
            }
        }
        gemm_fc<<<1024, 256, 0, stream>>>(hs, Wfcb, bfc, out);
    }
}